// Round 4
// baseline (85.414 us; speedup 1.0000x reference)
//
#include <hip/hip_runtime.h>
#include <hip/hip_bf16.h>
#include <math.h>

typedef __attribute__((ext_vector_type(8))) short short8;
typedef __attribute__((ext_vector_type(4))) float f32x4;

// ---------------- factorial tables (fp64) -------------------------
__constant__ double c_fact[20] = {
    1.0, 1.0, 2.0, 6.0, 24.0, 120.0, 720.0, 5040.0, 40320.0, 362880.0,
    3628800.0, 39916800.0, 479001600.0, 6227020800.0, 87178291200.0,
    1307674368000.0, 20922789888000.0, 355687428096000.0,
    6402373705728000.0, 121645100408832000.0};
__constant__ double c_invf[20] = {
    1.0, 1.0, 0.5, 0.16666666666666666, 0.041666666666666664,
    0.008333333333333333, 0.001388888888888889, 1.984126984126984e-4,
    2.48015873015873e-5, 2.755731922398589e-6, 2.755731922398589e-7,
    2.505210838544172e-8, 2.08767569878681e-9, 1.6059043836821613e-10,
    1.1470745597729725e-11, 7.647163731819816e-13, 4.779477332387385e-14,
    2.8114572543455206e-15, 1.5619206968586225e-16, 8.22063524662433e-18};

__device__ double cgd(int j1, int m1, int j2, int m2, int j3, int m3) {
  if (m1 + m2 != m3) return 0.0;
  double pre = (double)(2 * j3 + 1) * c_fact[j1 + j2 - j3] * c_fact[j1 - j2 + j3] *
               c_fact[-j1 + j2 + j3] * c_invf[j1 + j2 + j3 + 1];
  pre *= c_fact[j1 + m1] * c_fact[j1 - m1] * c_fact[j2 + m2] * c_fact[j2 - m2] *
         c_fact[j3 + m3] * c_fact[j3 - m3];
  int kmin = max(0, max(j2 - j3 - m1, j1 - j3 + m2));
  int kmax = min(j1 + j2 - j3, min(j1 - m1, j2 + m2));
  double s = 0.0;
  for (int k = kmin; k <= kmax; ++k) {
    double d = c_invf[k] * c_invf[j1 + j2 - j3 - k] * c_invf[j1 - m1 - k] *
               c_invf[j2 + m2 - k] * c_invf[j3 - j2 + m1 + k] * c_invf[j3 - j1 - m2 + k];
    s += ((k & 1) ? -d : d);
  }
  return sqrt(pre) * s;
}

__device__ double wstd(int l1, int l2, int l3, int i, int j, int k) {
  int m1 = i - l1, m2 = j - l2, m3 = k - l3;
  if (m1 + m2 + m3 != 0) return 0.0;
  int e = l1 - l2 - m3;
  double sgn = (e & 1) ? -1.0 : 1.0;
  return sgn / sqrt((double)(2 * l3 + 1)) * cgd(l1, m1, l2, m2, l3, -m3);
}

__device__ int qrow(int l, int a, int idx[2], double vr[2], double vi[2]) {
  const double s2 = 0.70710678118654752440;
  int m = a - l;
  if (m == 0) { idx[0] = l; vr[0] = 1.0; vi[0] = 0.0; return 1; }
  if (m > 0) {
    idx[0] = l + m; vr[0] = (m & 1) ? -s2 : s2; vi[0] = 0.0;
    idx[1] = l - m; vr[1] = s2;                 vi[1] = 0.0;
    return 2;
  }
  int mm = -m;
  idx[0] = l - mm; vr[0] = 0.0; vi[0] = s2;
  idx[1] = l + mm; vr[1] = 0.0; vi[1] = (mm & 1) ? s2 : -s2;
  return 2;
}

__device__ double w3j_real(int l1, int l2, int l3, int a, int b, int c) {
  int i1[2], i2[2], i3[2];
  double r1[2], s1[2], r2[2], s2v[2], r3[2], s3[2];
  int n1 = qrow(l1, a, i1, r1, s1);
  int n2 = qrow(l2, b, i2, r2, s2v);
  int n3 = qrow(l3, c, i3, r3, s3);
  double re = 0.0;
  for (int x = 0; x < n1; ++x)
    for (int y = 0; y < n2; ++y)
      for (int z = 0; z < n3; ++z) {
        double w = wstd(l1, l2, l3, i1[x], i2[y], i3[z]);
        if (w == 0.0) continue;
        double pr = r1[x] * r2[y] - s1[x] * s2v[y];
        double pi = r1[x] * s2v[y] + s1[x] * r2[y];
        double qr = pr * r3[z] - pi * s3[z];
        re += qr * w;
      }
  int L = l1 + l2 + l3;
  return ((L & 3) == 0) ? re : -re;
}

__device__ double sh_val(int k, int col) {
  const double PI_ = 3.14159265358979323846;
  double sgn = (k == 0 || k == 3) ? 1.0 : -1.0;
  if (col == 0) return 0.5 / sqrt(PI_);
  if (col == 1) return sgn * 0.25 * sqrt(15.0 / PI_);
  if (col == 3) return -0.25 * sqrt(5.0 / PI_);
  return 0.0;
}

__device__ __forceinline__ unsigned short bf16u(float x) {
  __hip_bfloat16 h = __float2bfloat16(x);
  return __builtin_bit_cast(unsigned short, h);
}
__device__ __forceinline__ float b2f(unsigned short u) {
  unsigned int v = ((unsigned int)u) << 16;
  return __builtin_bit_cast(float, v);
}

// ws layout (ushort): [0,22528) W3G frag-swizzled ; [22528,26624) M3G
__global__ void eq_setup(const float* __restrict__ w_agg, const float* __restrict__ w_tp,
                         const int* __restrict__ ph, const int* __restrict__ pw,
                         float* __restrict__ out, long long tail_off,
                         unsigned short* __restrict__ ws) {
  int gid = blockIdx.x * 256 + threadIdx.x;
  if (gid == 0) {
    out[tail_off]     = (float)(ph[0] * 4);
    out[tail_off + 1] = (float)(pw[0] * 4);
  }
  if (gid < 22528) {  // W3G: B-fragment element for K2
    int a = gid >> 10;
    int rem = gid & 1023;
    int nt = rem >> 9;
    int l = (rem >> 3) & 63;
    int e = rem & 7;
    int b = ((l >> 4) << 3) + e;   // k index (contraction over b)
    int c = nt * 16 + (l & 15);    // output col
    float v = 0.f;
    if (b < 22 && c < 22) {
      int l1 = (a < 9) ? 4 : 6, l2 = (b < 9) ? 4 : 6, l3 = (c < 9) ? 4 : 6;
      int a_ = (a < 9) ? a : a - 9, b_ = (b < 9) ? b : b - 9, c_ = (c < 9) ? c : c - 9;
      int idx = ((l1 == 6) ? 4 : 0) + ((l2 == 6) ? 2 : 0) + ((l3 == 6) ? 1 : 0);
      double alpha = sqrt((double)(2 * l3 + 1) / 4.0);
      v = (float)((double)w_tp[idx] * alpha * w3j_real(l1, l2, l3, a_, b_, c_));
    }
    ws[gid] = bf16u(v);
  } else if (gid < 26624) {  // M3G: B-fragment element for K1
    int s = gid - 22528;
    int km = s >> 10;
    int rem = s & 1023;
    int nt = rem >> 9;
    int l = (rem >> 3) & 63;
    int e = rem & 7;
    int a = ((l >> 4) << 3) + e;   // k index (contraction over a)
    int c = nt * 16 + (l & 15);    // output col
    float v = 0.f;
    if (a < 22 && c < 22) {
      int l1 = (a < 9) ? 4 : 6, l3 = (c < 9) ? 4 : 6;
      int a_ = (a < 9) ? a : a - 9, c_ = (c < 9) ? c : c - 9;
      double acc = 0.0;
      double alpha = sqrt((double)(2 * l3 + 1) / 3.0);
      if (l1 == l3) {
        int i = (l1 == 4) ? 0 : 3;
        acc += (double)w_agg[i] * alpha * sh_val(km, 0) * w3j_real(l1, 0, l3, a_, 0, c_);
      }
      {
        int i = (l1 == 4) ? ((l3 == 4) ? 1 : 2) : ((l3 == 4) ? 4 : 5);
        double t = 0.0;
        for (int bb = 0; bb < 5; ++bb) {
          double shv = sh_val(km, 1 + bb);
          if (shv != 0.0) t += shv * w3j_real(l1, 2, l3, a_, bb, c_);
        }
        acc += (double)w_agg[i] * alpha * t;
      }
      v = (float)acc;
    }
    ws[gid] = bf16u(v);
  }
}

__device__ __forceinline__ void load_lds16(const unsigned int* g, unsigned int* l) {
  __builtin_amdgcn_global_load_lds(
      (const __attribute__((address_space(1))) unsigned int*)g,
      (__attribute__((address_space(3))) unsigned int*)l, 16, 0, 0);
}

// ------- persistent main kernel: 512 blocks x 512 threads, tiles of 32 cells -------
__global__ __launch_bounds__(512, 4) void eq_main(
    const float* __restrict__ f4, const float* __restrict__ f6,
    const int* __restrict__ ph, const int* __restrict__ pw,
    const unsigned short* __restrict__ ws, float* __restrict__ out) {
  const int H = ph[0], Wc = pw[0];
  const int bx = (Wc + 31) >> 5;
  const long long ntiles = (long long)bx * H;

  __shared__ __align__(16) unsigned short WM[26624];   // W3s [0,22528) + M3s [22528,26624)
  __shared__ __align__(16) unsigned short FsB[1584];   // 2 rows x 33 cols x 24 (bf16)
  __shared__ __align__(16) unsigned short CtxV[4096];  // 128 rows x 32 (bf16): ctx then vout

  const int tid = threadIdx.x;
  const int wv = tid >> 6;
  const int l = tid & 63;

  // ---- stage WM via async global->LDS (linear, 16B/lane), once per block ----
  {
    const unsigned int* src = (const unsigned int*)ws;
    unsigned int* dstbase = (unsigned int*)WM;
#pragma unroll
    for (int i = 0; i < 7; ++i) {
      int chunk0 = i * 512 + wv * 64;  // wave-uniform
      if (chunk0 < 3328) {
        load_lds16(src + (chunk0 + l) * 4, dstbase + chunk0 * 4);
      }
    }
  }

  if ((long long)blockIdx.x >= ntiles) return;  // nothing to do (tiny images)

  const long long Npix = (long long)H * Wc * 16;
  const int Wr = Wc << 2;
  float* out6 = out + Npix * 9;

  // ---- prefetch features of first tile into registers ----
  float fr[4];
  {
    const long long t = blockIdx.x;
    const int y0 = (int)(t / bx);
    const int x0 = (int)(t - (long long)y0 * bx) << 5;
#pragma unroll
    for (int k = 0; k < 4; ++k) {
      int e = tid + k * 512;
      float v = 0.f;
      if (e < 1584) {
        int r = e / 792;
        int rem = e - r * 792;
        int col = rem / 24;
        int a = rem - col * 24;
        if (a < 22) {
          int yy = min(y0 + r, H - 1);
          int xx = min(x0 + col, Wc - 1);
          long long p = (long long)yy * Wc + xx;
          v = (a < 9) ? f4[p * 9 + a] : f6[p * 13 + (a - 9)];
        }
      }
      fr[k] = v;
    }
  }
  __syncthreads();  // WM staged (vmcnt drained) + visible to all waves

  const int l15 = l & 15;
  const int lg = l >> 4;
  const int q = l15 & 3;
  const int cellA = (wv << 2) + (l15 >> 2);  // cell of this lane's A-row
  const int cellD = (wv << 2) + lg;          // cell of this lane's D-rows
  const int a0 = lg << 3;                    // k-offset: 0,8,16,24

  // ---- hoist K1 M-fragments to registers (once per block) ----
  short8 mb[8];
#pragma unroll
  for (int km = 0; km < 4; ++km) {
    mb[2 * km]     = *(const short8*)&WM[22528 + (km * 2 + 0) * 512 + l * 8];
    mb[2 * km + 1] = *(const short8*)&WM[22528 + (km * 2 + 1) * 512 + l * 8];
  }

  for (long long t = blockIdx.x; t < ntiles; t += gridDim.x) {
    const int y0 = (int)(t / bx);
    const int x0 = (int)(t - (long long)y0 * bx) << 5;

    // ---- commit prefetched features to LDS (bf16) ----
#pragma unroll
    for (int k = 0; k < 4; ++k) {
      int e = tid + k * 512;
      if (e < 1584) FsB[e] = bf16u(fr[k]);
    }
    __syncthreads();  // barrier A

    // ---- K1: ctx = sum_k X_k * M_k ----
    f32x4 c0 = {0.f, 0.f, 0.f, 0.f}, c1 = {0.f, 0.f, 0.f, 0.f};
#pragma unroll
    for (int km = 0; km < 4; ++km) {
      short8 av = (short8)0;
      if (a0 < 24) {
        int dy = (km >> 1) & (q >> 1);
        int dx = km & q & 1;
        av = *(const short8*)&FsB[(dy * 33 + cellA + dx) * 24 + a0];
      }
      c0 = __builtin_amdgcn_mfma_f32_16x16x32_bf16(av, mb[2 * km], c0, 0, 0, 0);
      c1 = __builtin_amdgcn_mfma_f32_16x16x32_bf16(av, mb[2 * km + 1], c1, 0, 0, 0);
    }
    // write ctx (bf16, own wave's rows) + zero pad cols 22,23
#pragma unroll
    for (int r = 0; r < 4; ++r) {
      int row = wv * 16 + (lg << 2) + r;
      CtxV[row * 32 + l15] = bf16u(c0[r]);
      if (l15 < 6) CtxV[row * 32 + 16 + l15] = bf16u(c1[r]);
      else if (l15 < 8) CtxV[row * 32 + 16 + l15] = 0;
    }

    // ---- hoist F row (22 regs) and ctx fragment (wave-local LDS round-trip) ----
    float Fv[22];
    {
      const short8 f0 = *(const short8*)&FsB[cellA * 24 + 0];
      const short8 f1 = *(const short8*)&FsB[cellA * 24 + 8];
      const short8 f2 = *(const short8*)&FsB[cellA * 24 + 16];
#pragma unroll
      for (int j = 0; j < 8; ++j) {
        Fv[j] = b2f((unsigned short)f0[j]);
        Fv[8 + j] = b2f((unsigned short)f1[j]);
        if (j < 6) Fv[16 + j] = b2f((unsigned short)f2[j]);
      }
    }
    float cv[8];
    {
      short8 cvb = (short8)0;
      if (a0 < 24) cvb = *(const short8*)&CtxV[(wv * 16 + l15) * 32 + a0];
#pragma unroll
      for (int j = 0; j < 8; ++j) cv[j] = b2f((unsigned short)cvb[j]);
    }

    // ---- issue next-tile feature prefetch (hides under K2 + writer) ----
    {
      const long long tn = t + gridDim.x;
      if (tn < ntiles) {
        const int y0n = (int)(tn / bx);
        const int x0n = (int)(tn - (long long)y0n * bx) << 5;
#pragma unroll
        for (int k = 0; k < 4; ++k) {
          int e = tid + k * 512;
          float v = 0.f;
          if (e < 1584) {
            int r = e / 792;
            int rem = e - r * 792;
            int col = rem / 24;
            int a = rem - col * 24;
            if (a < 22) {
              int yy = min(y0n + r, H - 1);
              int xx = min(x0n + col, Wc - 1);
              long long p = (long long)yy * Wc + xx;
              v = (a < 9) ? f4[p * 9 + a] : f6[p * 13 + (a - 9)];
            }
          }
          fr[k] = v;
        }
      }
    }

    // ---- K2: out = sum_a F[a] * (ctx . W[a]) ; even/odd dual accumulators ----
    f32x4 oE0 = {0.f, 0.f, 0.f, 0.f}, oE1 = {0.f, 0.f, 0.f, 0.f};
    f32x4 oO0 = {0.f, 0.f, 0.f, 0.f}, oO1 = {0.f, 0.f, 0.f, 0.f};
#pragma unroll
    for (int ap = 0; ap < 11; ++ap) {
      {
        const int a = 2 * ap;
        const float s = Fv[a];
        short8 av;
#pragma unroll
        for (int j = 0; j < 8; ++j) av[j] = (short)bf16u(cv[j] * s);
        const short8 w0 = *(const short8*)&WM[a * 1024 + l * 8];
        const short8 w1 = *(const short8*)&WM[a * 1024 + 512 + l * 8];
        oE0 = __builtin_amdgcn_mfma_f32_16x16x32_bf16(av, w0, oE0, 0, 0, 0);
        oE1 = __builtin_amdgcn_mfma_f32_16x16x32_bf16(av, w1, oE1, 0, 0, 0);
      }
      {
        const int a = 2 * ap + 1;
        const float s = Fv[a];
        short8 av;
#pragma unroll
        for (int j = 0; j < 8; ++j) av[j] = (short)bf16u(cv[j] * s);
        const short8 w0 = *(const short8*)&WM[a * 1024 + l * 8];
        const short8 w1 = *(const short8*)&WM[a * 1024 + 512 + l * 8];
        oO0 = __builtin_amdgcn_mfma_f32_16x16x32_bf16(av, w0, oO0, 0, 0, 0);
        oO1 = __builtin_amdgcn_mfma_f32_16x16x32_bf16(av, w1, oO1, 0, 0, 0);
      }
    }

    // ---- epilogue: vout = out + residual F (bf16, own wave's rows) ----
    {
      const float r0 = b2f(FsB[cellD * 24 + l15]);
      const float r1 = (l15 < 6) ? b2f(FsB[cellD * 24 + 16 + l15]) : 0.f;
#pragma unroll
      for (int r = 0; r < 4; ++r) {
        int row = wv * 16 + (lg << 2) + r;
        CtxV[row * 32 + l15] = bf16u(oE0[r] + oO0[r] + r0);
        if (l15 < 6) CtxV[row * 32 + 16 + l15] = bf16u(oE1[r] + oO1[r] + r1);
      }
    }
    __syncthreads();  // barrier B

    // ---- coalesced writer: wave wv -> HR row (wv>>1), x-half (wv&1) ----
    {
      const int ry = wv >> 1;
      const int h = wv & 1;
      const long long y4 = (long long)(y0 << 2) + ry;
      const int xbase = (x0 << 2) + (h << 6);
      const int xmax = (min(32, Wc - x0) << 2);
      const int qy = (ry == 3) ? 2 : 0;
      const long long b4 = ((long long)y4 * Wr + xbase) * 9;
      const long long b6 = ((long long)y4 * Wr + xbase) * 13;
#pragma unroll
      for (int s = 0; s < 9; ++s) {
        int idx = s * 64 + l;
        int pxh = idx / 9;
        int ch = idx - pxh * 9;
        int px = (h << 6) + pxh;
        if (px < xmax) {
          int cl = px >> 2;
          int qq = qy | (((px & 3) == 3) ? 1 : 0);
          out[b4 + idx] = b2f(CtxV[((cl << 2) + qq) * 32 + ch]);
        }
      }
#pragma unroll
      for (int s = 0; s < 13; ++s) {
        int idx = s * 64 + l;
        int pxh = idx / 13;
        int ch = idx - pxh * 13;
        int px = (h << 6) + pxh;
        if (px < xmax) {
          int cl = px >> 2;
          int qq = qy | (((px & 3) == 3) ? 1 : 0);
          out6[b6 + idx] = b2f(CtxV[((cl << 2) + qq) * 32 + 9 + ch]);
        }
      }
    }
  }
}

extern "C" void kernel_launch(void* const* d_in, const int* in_sizes, int n_in,
                              void* d_out, int out_size, void* d_ws, size_t ws_size,
                              hipStream_t stream) {
  const float* f4 = (const float*)d_in[0];
  const float* f6 = (const float*)d_in[1];
  const int* ph = (const int*)d_in[2];
  const int* pw = (const int*)d_in[3];
  const float* wagg = (const float*)d_in[4];
  const float* wtp = (const float*)d_in[5];
  float* out = (float*)d_out;
  unsigned short* wsu = (unsigned short*)d_ws;

  long long tail = (long long)out_size - 2;

  eq_setup<<<104, 256, 0, stream>>>(wagg, wtp, ph, pw, out, tail, wsu);
  eq_main<<<512, 512, 0, stream>>>(f4, f6, ph, pw, wsu, out);
}

// Round 5
// 73.979 us; speedup vs baseline: 1.1546x; 1.1546x over previous
//
#include <hip/hip_runtime.h>
#include <hip/hip_bf16.h>
#include <math.h>

typedef __attribute__((ext_vector_type(8))) short short8;
typedef __attribute__((ext_vector_type(4))) float f32x4;

// ---------------- factorial tables (fp64) -------------------------
__constant__ double c_fact[20] = {
    1.0, 1.0, 2.0, 6.0, 24.0, 120.0, 720.0, 5040.0, 40320.0, 362880.0,
    3628800.0, 39916800.0, 479001600.0, 6227020800.0, 87178291200.0,
    1307674368000.0, 20922789888000.0, 355687428096000.0,
    6402373705728000.0, 121645100408832000.0};
__constant__ double c_invf[20] = {
    1.0, 1.0, 0.5, 0.16666666666666666, 0.041666666666666664,
    0.008333333333333333, 0.001388888888888889, 1.984126984126984e-4,
    2.48015873015873e-5, 2.755731922398589e-6, 2.755731922398589e-7,
    2.505210838544172e-8, 2.08767569878681e-9, 1.6059043836821613e-10,
    1.1470745597729725e-11, 7.647163731819816e-13, 4.779477332387385e-14,
    2.8114572543455206e-15, 1.5619206968586225e-16, 8.22063524662433e-18};

__device__ double cgd(int j1, int m1, int j2, int m2, int j3, int m3) {
  if (m1 + m2 != m3) return 0.0;
  double pre = (double)(2 * j3 + 1) * c_fact[j1 + j2 - j3] * c_fact[j1 - j2 + j3] *
               c_fact[-j1 + j2 + j3] * c_invf[j1 + j2 + j3 + 1];
  pre *= c_fact[j1 + m1] * c_fact[j1 - m1] * c_fact[j2 + m2] * c_fact[j2 - m2] *
         c_fact[j3 + m3] * c_fact[j3 - m3];
  int kmin = max(0, max(j2 - j3 - m1, j1 - j3 + m2));
  int kmax = min(j1 + j2 - j3, min(j1 - m1, j2 + m2));
  double s = 0.0;
  for (int k = kmin; k <= kmax; ++k) {
    double d = c_invf[k] * c_invf[j1 + j2 - j3 - k] * c_invf[j1 - m1 - k] *
               c_invf[j2 + m2 - k] * c_invf[j3 - j2 + m1 + k] * c_invf[j3 - j1 - m2 + k];
    s += ((k & 1) ? -d : d);
  }
  return sqrt(pre) * s;
}

__device__ double wstd(int l1, int l2, int l3, int i, int j, int k) {
  int m1 = i - l1, m2 = j - l2, m3 = k - l3;
  if (m1 + m2 + m3 != 0) return 0.0;
  int e = l1 - l2 - m3;
  double sgn = (e & 1) ? -1.0 : 1.0;
  return sgn / sqrt((double)(2 * l3 + 1)) * cgd(l1, m1, l2, m2, l3, -m3);
}

__device__ int qrow(int l, int a, int idx[2], double vr[2], double vi[2]) {
  const double s2 = 0.70710678118654752440;
  int m = a - l;
  if (m == 0) { idx[0] = l; vr[0] = 1.0; vi[0] = 0.0; return 1; }
  if (m > 0) {
    idx[0] = l + m; vr[0] = (m & 1) ? -s2 : s2; vi[0] = 0.0;
    idx[1] = l - m; vr[1] = s2;                 vi[1] = 0.0;
    return 2;
  }
  int mm = -m;
  idx[0] = l - mm; vr[0] = 0.0; vi[0] = s2;
  idx[1] = l + mm; vr[1] = 0.0; vi[1] = (mm & 1) ? s2 : -s2;
  return 2;
}

__device__ double w3j_real(int l1, int l2, int l3, int a, int b, int c) {
  int i1[2], i2[2], i3[2];
  double r1[2], s1[2], r2[2], s2v[2], r3[2], s3[2];
  int n1 = qrow(l1, a, i1, r1, s1);
  int n2 = qrow(l2, b, i2, r2, s2v);
  int n3 = qrow(l3, c, i3, r3, s3);
  double re = 0.0;
  for (int x = 0; x < n1; ++x)
    for (int y = 0; y < n2; ++y)
      for (int z = 0; z < n3; ++z) {
        double w = wstd(l1, l2, l3, i1[x], i2[y], i3[z]);
        if (w == 0.0) continue;
        double pr = r1[x] * r2[y] - s1[x] * s2v[y];
        double pi = r1[x] * s2v[y] + s1[x] * r2[y];
        double qr = pr * r3[z] - pi * s3[z];
        re += qr * w;
      }
  int L = l1 + l2 + l3;
  return ((L & 3) == 0) ? re : -re;
}

__device__ double sh_val(int k, int col) {
  const double PI_ = 3.14159265358979323846;
  double sgn = (k == 0 || k == 3) ? 1.0 : -1.0;
  if (col == 0) return 0.5 / sqrt(PI_);
  if (col == 1) return sgn * 0.25 * sqrt(15.0 / PI_);
  if (col == 3) return -0.25 * sqrt(5.0 / PI_);
  return 0.0;
}

__device__ __forceinline__ unsigned short bf16u(float x) {
  __hip_bfloat16 h = __float2bfloat16(x);
  return __builtin_bit_cast(unsigned short, h);
}
__device__ __forceinline__ float b2f(unsigned short u) {
  unsigned int v = ((unsigned int)u) << 16;
  return __builtin_bit_cast(float, v);
}

// ws layout (ushort): [0,22528) W3G frag-swizzled ; [22528,26624) M3G
__global__ void eq_setup(const float* __restrict__ w_agg, const float* __restrict__ w_tp,
                         const int* __restrict__ ph, const int* __restrict__ pw,
                         float* __restrict__ out, long long tail_off,
                         unsigned short* __restrict__ ws) {
  int gid = blockIdx.x * 256 + threadIdx.x;
  if (gid == 0) {
    out[tail_off]     = (float)(ph[0] * 4);
    out[tail_off + 1] = (float)(pw[0] * 4);
  }
  if (gid < 22528) {  // W3G: B-fragment element for K2
    int a = gid >> 10;
    int rem = gid & 1023;
    int nt = rem >> 9;
    int l = (rem >> 3) & 63;
    int e = rem & 7;
    int b = ((l >> 4) << 3) + e;   // k index (contraction over b)
    int c = nt * 16 + (l & 15);    // output col
    float v = 0.f;
    if (b < 22 && c < 22) {
      int l1 = (a < 9) ? 4 : 6, l2 = (b < 9) ? 4 : 6, l3 = (c < 9) ? 4 : 6;
      int a_ = (a < 9) ? a : a - 9, b_ = (b < 9) ? b : b - 9, c_ = (c < 9) ? c : c - 9;
      int idx = ((l1 == 6) ? 4 : 0) + ((l2 == 6) ? 2 : 0) + ((l3 == 6) ? 1 : 0);
      double alpha = sqrt((double)(2 * l3 + 1) / 4.0);
      v = (float)((double)w_tp[idx] * alpha * w3j_real(l1, l2, l3, a_, b_, c_));
    }
    ws[gid] = bf16u(v);
  } else if (gid < 26624) {  // M3G: B-fragment element for K1
    int s = gid - 22528;
    int km = s >> 10;
    int rem = s & 1023;
    int nt = rem >> 9;
    int l = (rem >> 3) & 63;
    int e = rem & 7;
    int a = ((l >> 4) << 3) + e;   // k index (contraction over a)
    int c = nt * 16 + (l & 15);    // output col
    float v = 0.f;
    if (a < 22 && c < 22) {
      int l1 = (a < 9) ? 4 : 6, l3 = (c < 9) ? 4 : 6;
      int a_ = (a < 9) ? a : a - 9, c_ = (c < 9) ? c : c - 9;
      double acc = 0.0;
      double alpha = sqrt((double)(2 * l3 + 1) / 3.0);
      if (l1 == l3) {
        int i = (l1 == 4) ? 0 : 3;
        acc += (double)w_agg[i] * alpha * sh_val(km, 0) * w3j_real(l1, 0, l3, a_, 0, c_);
      }
      {
        int i = (l1 == 4) ? ((l3 == 4) ? 1 : 2) : ((l3 == 4) ? 4 : 5);
        double t = 0.0;
        for (int bb = 0; bb < 5; ++bb) {
          double shv = sh_val(km, 1 + bb);
          if (shv != 0.0) t += shv * w3j_real(l1, 2, l3, a_, bb, c_);
        }
        acc += (double)w_agg[i] * alpha * t;
      }
      v = (float)acc;
    }
    ws[gid] = bf16u(v);
  }
}

__device__ __forceinline__ void load_lds16(const unsigned int* g, unsigned int* l) {
  __builtin_amdgcn_global_load_lds(
      (const __attribute__((address_space(1))) unsigned int*)g,
      (__attribute__((address_space(3))) unsigned int*)l, 16, 0, 0);
}

#define WAVE_LDS_FENCE() do { \
    asm volatile("s_waitcnt lgkmcnt(0)" ::: "memory"); \
    __builtin_amdgcn_sched_barrier(0); } while (0)

// ------- main kernel: 32 cells/block, 512 threads; each WAVE owns 4 cells,
// ------- zero intra-tile barriers (wave-synchronous LDS comms only) -------
__global__ __launch_bounds__(512, 4) void eq_main(
    const float* __restrict__ f4, const float* __restrict__ f6,
    const int* __restrict__ ph, const int* __restrict__ pw,
    const unsigned short* __restrict__ ws, float* __restrict__ out) {
  const int H = ph[0], Wc = pw[0];
  const int bx = (Wc + 31) >> 5;
  const long long ntiles = (long long)bx * H;

  // LDS: W table [0,22528) ush; per-wave scratch 1024 ush each:
  //   F region   [FOFF, FOFF+240): 10 px x 24 ch bf16
  //   ctx/vout   [COFF, COFF+384): 16 rows x 24 ch bf16
  __shared__ __align__(16) unsigned short LDS[30720];  // 61440 B

  const int tid = threadIdx.x;
  const int wv = tid >> 6;
  const int l = tid & 63;
  const long long t = blockIdx.x;

  // ---- stage W table via async global->LDS DMA (44 KiB, linear) ----
  {
    const unsigned int* src = (const unsigned int*)ws;
    unsigned int* dst = (unsigned int*)LDS;
#pragma unroll
    for (int i = 0; i < 6; ++i) {
      int chunk = i * 8 + wv;  // wave-uniform; 1 KiB per chunk
      if (chunk < 44) load_lds16(src + chunk * 256 + l * 4, dst + chunk * 256);
    }
  }

  // ---- K1 M-fragments straight from global (L2-hot) ----
  short8 mb[8];
  {
    const short8* msrc = (const short8*)(ws + 22528);
#pragma unroll
    for (int i = 0; i < 8; ++i) mb[i] = msrc[i * 64 + l];
  }

  // ---- per-wave feature staging: 2 rows x 5 cols x 22 ch -> bf16 LDS ----
  const int y0 = (int)(t / bx);
  const int xC0 = (int)(t - (long long)y0 * bx) << 5;
  const int cw0 = xC0 + (wv << 2);  // this wave's first coarse cell col
  const int FOFF = 22528 + (wv << 10);
  const int COFF = FOFF + 256;
#pragma unroll
  for (int k = 0; k < 2; ++k) {
    int e = k * 64 + l;
    if (e < 110) {
      int px = e / 11, pr = e - px * 11;
      int dyR = px / 5, col = px - dyR * 5;
      int yy = min(y0 + dyR, H - 1);
      int xx = min(cw0 + col, Wc - 1);
      long long p = (long long)yy * Wc + xx;
      int ca = 2 * pr, cb = ca + 1;
      float v0 = (ca < 9) ? f4[p * 9 + ca] : f6[p * 13 + ca - 9];
      float v1 = (cb < 9) ? f4[p * 9 + cb] : f6[p * 13 + cb - 9];
      unsigned int pk = (unsigned int)bf16u(v0) | ((unsigned int)bf16u(v1) << 16);
      *(unsigned int*)&LDS[FOFF + px * 24 + ca] = pk;
    } else if (e < 120) {
      int px = e - 110;
      *(unsigned int*)&LDS[FOFF + px * 24 + 22] = 0u;  // pad chans 22,23
    }
  }

  __syncthreads();  // the ONLY block barrier: W DMA + all staging drained
  if (t >= ntiles) return;

  const int l15 = l & 15;
  const int lg = l >> 4;          // 0..3
  const int q = l15 & 3;          // cls of this lane's A-row
  const int lcell = l15 >> 2;     // cell (0..3) of this lane's A-row
  const int a0 = lg << 3;         // fragment k-offset: 0,8,16,24

  // ---- K1: ctx = sum_k X_k * M_k (16 rows = 4 cells x 4 cls) ----
  f32x4 c0 = {0.f, 0.f, 0.f, 0.f}, c1 = {0.f, 0.f, 0.f, 0.f};
#pragma unroll
  for (int km = 0; km < 4; ++km) {
    short8 av = (short8)0;
    if (a0 < 24) {
      int dy = (km >> 1) & (q >> 1);
      int dx = km & q & 1;
      av = *(const short8*)&LDS[FOFF + (dy * 5 + lcell + dx) * 24 + a0];
    }
    c0 = __builtin_amdgcn_mfma_f32_16x16x32_bf16(av, mb[2 * km], c0, 0, 0, 0);
    c1 = __builtin_amdgcn_mfma_f32_16x16x32_bf16(av, mb[2 * km + 1], c1, 0, 0, 0);
  }

  // ---- ctx transpose via per-wave LDS (D: col=pixel(l15), row=chan) ----
#pragma unroll
  for (int r = 0; r < 4; ++r) {
    LDS[COFF + l15 * 24 + (lg << 2) + r] = bf16u(c0[r]);
    int ch1 = 16 + (lg << 2) + r;
    if (ch1 < 22) LDS[COFF + l15 * 24 + ch1] = bf16u(c1[r]);
  }
  if (lg == 0) *(unsigned int*)&LDS[COFF + l15 * 24 + 22] = 0u;  // pad
  WAVE_LDS_FENCE();

  // ---- gather K2 A-source: ctx row (8 chans at a0) + F row (packed) ----
  float cv[8];
  {
    short8 cvb = (short8)0;
    if (a0 < 24) cvb = *(const short8*)&LDS[COFF + l15 * 24 + a0];
#pragma unroll
    for (int j = 0; j < 8; ++j) cv[j] = (a0 < 24) ? b2f((unsigned short)cvb[j]) : 0.f;
  }
  unsigned int fvp[11];  // packed bf16 pairs of center-pixel F row
  {
    const unsigned int* fp = (const unsigned int*)&LDS[FOFF + lcell * 24];
#pragma unroll
    for (int j = 0; j < 11; ++j) fvp[j] = fp[j];
  }

  // ---- K2: out = sum_a F[a] * (ctx . W[a]); even/odd dual accumulators ----
  f32x4 oE0 = {0.f, 0.f, 0.f, 0.f}, oE1 = {0.f, 0.f, 0.f, 0.f};
  f32x4 oO0 = {0.f, 0.f, 0.f, 0.f}, oO1 = {0.f, 0.f, 0.f, 0.f};
#pragma unroll
  for (int ap = 0; ap < 11; ++ap) {
    const float sE = __builtin_bit_cast(float, fvp[ap] << 16);          // even chan
    const float sO = __builtin_bit_cast(float, fvp[ap] & 0xffff0000u);  // odd chan
    {
      const int a = 2 * ap;
      short8 av;
#pragma unroll
      for (int j = 0; j < 8; ++j) av[j] = (short)bf16u(cv[j] * sE);
      const short8 w0 = *(const short8*)&LDS[a * 1024 + l * 8];
      const short8 w1 = *(const short8*)&LDS[a * 1024 + 512 + l * 8];
      oE0 = __builtin_amdgcn_mfma_f32_16x16x32_bf16(av, w0, oE0, 0, 0, 0);
      oE1 = __builtin_amdgcn_mfma_f32_16x16x32_bf16(av, w1, oE1, 0, 0, 0);
    }
    {
      const int a = 2 * ap + 1;
      short8 av;
#pragma unroll
      for (int j = 0; j < 8; ++j) av[j] = (short)bf16u(cv[j] * sO);
      const short8 w0 = *(const short8*)&LDS[a * 1024 + l * 8];
      const short8 w1 = *(const short8*)&LDS[a * 1024 + 512 + l * 8];
      oO0 = __builtin_amdgcn_mfma_f32_16x16x32_bf16(av, w0, oO0, 0, 0, 0);
      oO1 = __builtin_amdgcn_mfma_f32_16x16x32_bf16(av, w1, oO1, 0, 0, 0);
    }
  }

  // ---- epilogue: vout = out + residual F (D: col=chan(l15), row=pixel) ----
  {
    const float r4 = b2f(LDS[FOFF + lg * 24 + l15]);
    const float r6 = (l15 < 6) ? b2f(LDS[FOFF + lg * 24 + 16 + l15]) : 0.f;
#pragma unroll
    for (int r = 0; r < 4; ++r) {
      int n = (lg << 2) + r;  // pixel row within wave's 16
      LDS[COFF + n * 24 + l15] = bf16u(oE0[r] + oO0[r] + r4);
      if (l15 < 6) LDS[COFF + n * 24 + 16 + l15] = bf16u(oE1[r] + oO1[r] + r6);
    }
  }
  WAVE_LDS_FENCE();

  // ---- writer: wave's 4 cells -> HR rows 4*y0..+3, 16 px wide ----
  {
    const int Wr = Wc << 2;
    const long long Npix = (long long)H * Wc * 16;
    float* out6 = out + Npix * 9;
    const int vx = max(min(4, Wc - cw0), 0) << 2;  // valid HR px in this wave
    const long long rb = (long long)(y0 << 2) * Wr + ((long long)cw0 << 2);
#pragma unroll
    for (int s = 0; s < 9; ++s) {
      int idx = s * 64 + l;
      int ry = idx / 144;
      int rem = idx - ry * 144;
      int px = rem / 9;
      if (px < vx) {
        int n = (px & ~3) + ((ry == 3) ? 2 : 0) + (((px & 3) == 3) ? 1 : 0);
        int ch = rem - px * 9;
        out[(rb + (long long)ry * Wr) * 9 + rem] = b2f(LDS[COFF + n * 24 + ch]);
      }
    }
#pragma unroll
    for (int s = 0; s < 13; ++s) {
      int idx = s * 64 + l;
      int ry = idx / 208;
      int rem = idx - ry * 208;
      int px = rem / 13;
      if (px < vx) {
        int n = (px & ~3) + ((ry == 3) ? 2 : 0) + (((px & 3) == 3) ? 1 : 0);
        int ch = rem - px * 13;
        out6[(rb + (long long)ry * Wr) * 13 + rem] = b2f(LDS[COFF + n * 24 + 9 + ch]);
      }
    }
  }
}

extern "C" void kernel_launch(void* const* d_in, const int* in_sizes, int n_in,
                              void* d_out, int out_size, void* d_ws, size_t ws_size,
                              hipStream_t stream) {
  const float* f4 = (const float*)d_in[0];
  const float* f6 = (const float*)d_in[1];
  const int* ph = (const int*)d_in[2];
  const int* pw = (const int*)d_in[3];
  const float* wagg = (const float*)d_in[4];
  const float* wtp = (const float*)d_in[5];
  float* out = (float*)d_out;
  unsigned short* wsu = (unsigned short*)d_ws;

  long long HW = (long long)in_sizes[0] / 9;
  long long tail = (long long)out_size - 2;

  eq_setup<<<104, 256, 0, stream>>>(wagg, wtp, ph, pw, out, tail, wsu);

  int S = (int)(sqrt((double)HW) + 0.5);
  long long nb;
  if ((long long)S * S == HW) {
    nb = (long long)((S + 31) / 32) * S;  // square image (the bench case)
  } else {
    nb = HW;  // conservative cover; excess blocks exit after the barrier
  }
  eq_main<<<(int)nb, 512, 0, stream>>>(f4, f6, ph, pw, wsu, out);
}

// Round 6
// 63.100 us; speedup vs baseline: 1.3536x; 1.1724x over previous
//
#include <hip/hip_runtime.h>
#include <hip/hip_bf16.h>
#include <math.h>

typedef __attribute__((ext_vector_type(8))) short short8;
typedef __attribute__((ext_vector_type(4))) float f32x4;

// ---------------- factorial tables (fp64) -------------------------
__constant__ double c_fact[20] = {
    1.0, 1.0, 2.0, 6.0, 24.0, 120.0, 720.0, 5040.0, 40320.0, 362880.0,
    3628800.0, 39916800.0, 479001600.0, 6227020800.0, 87178291200.0,
    1307674368000.0, 20922789888000.0, 355687428096000.0,
    6402373705728000.0, 121645100408832000.0};
__constant__ double c_invf[20] = {
    1.0, 1.0, 0.5, 0.16666666666666666, 0.041666666666666664,
    0.008333333333333333, 0.001388888888888889, 1.984126984126984e-4,
    2.48015873015873e-5, 2.755731922398589e-6, 2.755731922398589e-7,
    2.505210838544172e-8, 2.08767569878681e-9, 1.6059043836821613e-10,
    1.1470745597729725e-11, 7.647163731819816e-13, 4.779477332387385e-14,
    2.8114572543455206e-15, 1.5619206968586225e-16, 8.22063524662433e-18};

__device__ double cgd(int j1, int m1, int j2, int m2, int j3, int m3) {
  if (m1 + m2 != m3) return 0.0;
  double pre = (double)(2 * j3 + 1) * c_fact[j1 + j2 - j3] * c_fact[j1 - j2 + j3] *
               c_fact[-j1 + j2 + j3] * c_invf[j1 + j2 + j3 + 1];
  pre *= c_fact[j1 + m1] * c_fact[j1 - m1] * c_fact[j2 + m2] * c_fact[j2 - m2] *
         c_fact[j3 + m3] * c_fact[j3 - m3];
  int kmin = max(0, max(j2 - j3 - m1, j1 - j3 + m2));
  int kmax = min(j1 + j2 - j3, min(j1 - m1, j2 + m2));
  double s = 0.0;
  for (int k = kmin; k <= kmax; ++k) {
    double d = c_invf[k] * c_invf[j1 + j2 - j3 - k] * c_invf[j1 - m1 - k] *
               c_invf[j2 + m2 - k] * c_invf[j3 - j2 + m1 + k] * c_invf[j3 - j1 - m2 + k];
    s += ((k & 1) ? -d : d);
  }
  return sqrt(pre) * s;
}

__device__ double wstd(int l1, int l2, int l3, int i, int j, int k) {
  int m1 = i - l1, m2 = j - l2, m3 = k - l3;
  if (m1 + m2 + m3 != 0) return 0.0;
  int e = l1 - l2 - m3;
  double sgn = (e & 1) ? -1.0 : 1.0;
  return sgn / sqrt((double)(2 * l3 + 1)) * cgd(l1, m1, l2, m2, l3, -m3);
}

__device__ int qrow(int l, int a, int idx[2], double vr[2], double vi[2]) {
  const double s2 = 0.70710678118654752440;
  int m = a - l;
  if (m == 0) { idx[0] = l; vr[0] = 1.0; vi[0] = 0.0; return 1; }
  if (m > 0) {
    idx[0] = l + m; vr[0] = (m & 1) ? -s2 : s2; vi[0] = 0.0;
    idx[1] = l - m; vr[1] = s2;                 vi[1] = 0.0;
    return 2;
  }
  int mm = -m;
  idx[0] = l - mm; vr[0] = 0.0; vi[0] = s2;
  idx[1] = l + mm; vr[1] = 0.0; vi[1] = (mm & 1) ? s2 : -s2;
  return 2;
}

__device__ double w3j_real(int l1, int l2, int l3, int a, int b, int c) {
  int i1[2], i2[2], i3[2];
  double r1[2], s1[2], r2[2], s2v[2], r3[2], s3[2];
  int n1 = qrow(l1, a, i1, r1, s1);
  int n2 = qrow(l2, b, i2, r2, s2v);
  int n3 = qrow(l3, c, i3, r3, s3);
  double re = 0.0;
  for (int x = 0; x < n1; ++x)
    for (int y = 0; y < n2; ++y)
      for (int z = 0; z < n3; ++z) {
        double w = wstd(l1, l2, l3, i1[x], i2[y], i3[z]);
        if (w == 0.0) continue;
        double pr = r1[x] * r2[y] - s1[x] * s2v[y];
        double pi = r1[x] * s2v[y] + s1[x] * r2[y];
        double qr = pr * r3[z] - pi * s3[z];
        re += qr * w;
      }
  int L = l1 + l2 + l3;
  return ((L & 3) == 0) ? re : -re;
}

__device__ double sh_val(int k, int col) {
  const double PI_ = 3.14159265358979323846;
  double sgn = (k == 0 || k == 3) ? 1.0 : -1.0;
  if (col == 0) return 0.5 / sqrt(PI_);
  if (col == 1) return sgn * 0.25 * sqrt(15.0 / PI_);
  if (col == 3) return -0.25 * sqrt(5.0 / PI_);
  return 0.0;
}

__device__ __forceinline__ unsigned short bf16u(float x) {
  __hip_bfloat16 h = __float2bfloat16(x);
  return __builtin_bit_cast(unsigned short, h);
}
__device__ __forceinline__ float b2f(unsigned short u) {
  unsigned int v = ((unsigned int)u) << 16;
  return __builtin_bit_cast(float, v);
}

// ws layout: bytes [0, 22528) = W3G fp8 frag-swizzled;
//            ushort offset 11264..15360 = M3G bf16 (4096 ush)
__global__ void eq_setup(const float* __restrict__ w_agg, const float* __restrict__ w_tp,
                         const int* __restrict__ ph, const int* __restrict__ pw,
                         float* __restrict__ out, long long tail_off,
                         unsigned short* __restrict__ ws) {
  int gid = blockIdx.x * 256 + threadIdx.x;
  if (gid == 0) {
    out[tail_off]     = (float)(ph[0] * 4);
    out[tail_off + 1] = (float)(pw[0] * 4);
  }
  if (gid < 22528) {  // W3G: fp8 B-fragment byte for K2
    int a = gid >> 10;
    int rem = gid & 1023;
    int nt = rem >> 9;
    int l = (rem >> 3) & 63;
    int e = rem & 7;
    int b = ((l >> 4) << 3) + e;   // k index (contraction over b)
    int c = nt * 16 + (l & 15);    // output col
    float v = 0.f;
    if (b < 22 && c < 22) {
      int l1 = (a < 9) ? 4 : 6, l2 = (b < 9) ? 4 : 6, l3 = (c < 9) ? 4 : 6;
      int a_ = (a < 9) ? a : a - 9, b_ = (b < 9) ? b : b - 9, c_ = (c < 9) ? c : c - 9;
      int idx = ((l1 == 6) ? 4 : 0) + ((l2 == 6) ? 2 : 0) + ((l3 == 6) ? 1 : 0);
      double alpha = sqrt((double)(2 * l3 + 1) / 4.0);
      v = (float)((double)w_tp[idx] * alpha * w3j_real(l1, l2, l3, a_, b_, c_));
    }
    int pk = __builtin_amdgcn_cvt_pk_fp8_f32(v, 0.f, 0, 0);
    ((unsigned char*)ws)[gid] = (unsigned char)(pk & 0xff);
  } else if (gid < 26624) {  // M3G: bf16 B-fragment element for K1
    int s = gid - 22528;
    int km = s >> 10;
    int rem = s & 1023;
    int nt = rem >> 9;
    int l = (rem >> 3) & 63;
    int e = rem & 7;
    int a = ((l >> 4) << 3) + e;   // k index (contraction over a)
    int c = nt * 16 + (l & 15);    // output col
    float v = 0.f;
    if (a < 22 && c < 22) {
      int l1 = (a < 9) ? 4 : 6, l3 = (c < 9) ? 4 : 6;
      int a_ = (a < 9) ? a : a - 9, c_ = (c < 9) ? c : c - 9;
      double acc = 0.0;
      double alpha = sqrt((double)(2 * l3 + 1) / 3.0);
      if (l1 == l3) {
        int i = (l1 == 4) ? 0 : 3;
        acc += (double)w_agg[i] * alpha * sh_val(km, 0) * w3j_real(l1, 0, l3, a_, 0, c_);
      }
      {
        int i = (l1 == 4) ? ((l3 == 4) ? 1 : 2) : ((l3 == 4) ? 4 : 5);
        double t = 0.0;
        for (int bb = 0; bb < 5; ++bb) {
          double shv = sh_val(km, 1 + bb);
          if (shv != 0.0) t += shv * w3j_real(l1, 2, l3, a_, bb, c_);
        }
        acc += (double)w_agg[i] * alpha * t;
      }
      v = (float)acc;
    }
    ws[11264 + s] = bf16u(v);
  }
}

__device__ __forceinline__ void load_lds16(const unsigned int* g, unsigned int* l) {
  __builtin_amdgcn_global_load_lds(
      (const __attribute__((address_space(1))) unsigned int*)g,
      (__attribute__((address_space(3))) unsigned int*)l, 16, 0, 0);
}

#define WAVE_LDS_FENCE() do { \
    asm volatile("s_waitcnt lgkmcnt(0)" ::: "memory"); \
    __builtin_amdgcn_sched_barrier(0); } while (0)

// ------- main kernel: 32 cells/block, 512 threads; each WAVE owns 4 cells,
// ------- one block barrier; fp8 W table; per-wave 512-ush overlaid scratch -------
__global__ __launch_bounds__(512, 8) void eq_main(
    const float* __restrict__ f4, const float* __restrict__ f6,
    const int* __restrict__ ph, const int* __restrict__ pw,
    const unsigned short* __restrict__ ws, float* __restrict__ out) {
  const int H = ph[0], Wc = pw[0];
  const int bx = (Wc + 31) >> 5;
  const long long ntiles = (long long)bx * H;

  // LDS (ushort units): W fp8 [0, 11264); per-wave scratch 512 ush at 11264+wv*512:
  //   F region  [SOFF, SOFF+240): 10 px x 24 ch bf16   (phase 1)
  //   ctx/vout  [SOFF, SOFF+384): 16 rows x 24 ch bf16 (phases 2+, overlays F)
  __shared__ __align__(16) unsigned short LDS[15360];  // 30720 B

  const int tid = threadIdx.x;
  const int wv = tid >> 6;
  const int l = tid & 63;
  const long long t = blockIdx.x;

  // ---- stage W table via async global->LDS DMA (22 KiB, linear) ----
  {
    const unsigned int* src = (const unsigned int*)ws;
    unsigned int* dst = (unsigned int*)LDS;
#pragma unroll
    for (int i = 0; i < 3; ++i) {
      int chunk = i * 8 + wv;  // wave-uniform; 1 KiB per chunk
      if (chunk < 22) load_lds16(src + chunk * 256 + l * 4, dst + chunk * 256);
    }
  }

  // ---- K1 M-fragments straight from global (L2-hot, bf16) ----
  short8 mb[8];
  {
    const short8* msrc = (const short8*)(ws + 11264);
#pragma unroll
    for (int i = 0; i < 8; ++i) mb[i] = msrc[i * 64 + l];
  }

  // ---- per-wave feature staging: 2 rows x 5 cols x 22 ch -> bf16 LDS ----
  const int y0 = (int)(t / bx);
  const int xC0 = (int)(t - (long long)y0 * bx) << 5;
  const int cw0 = xC0 + (wv << 2);          // this wave's first coarse cell col
  const int SOFF = 11264 + (wv << 9);       // 512-ush scratch slot
#pragma unroll
  for (int k = 0; k < 2; ++k) {
    int e = k * 64 + l;
    if (e < 110) {
      int px = e / 11, pr = e - px * 11;
      int dyR = px / 5, col = px - dyR * 5;
      int yy = min(y0 + dyR, H - 1);
      int xx = min(cw0 + col, Wc - 1);
      long long p = (long long)yy * Wc + xx;
      int ca = 2 * pr, cb = ca + 1;
      float v0 = (ca < 9) ? f4[p * 9 + ca] : f6[p * 13 + ca - 9];
      float v1 = (cb < 9) ? f4[p * 9 + cb] : f6[p * 13 + cb - 9];
      unsigned int pk = (unsigned int)bf16u(v0) | ((unsigned int)bf16u(v1) << 16);
      *(unsigned int*)&LDS[SOFF + px * 24 + ca] = pk;
    } else if (e < 120) {
      int px = e - 110;
      *(unsigned int*)&LDS[SOFF + px * 24 + 22] = 0u;  // pad chans 22,23
    }
  }

  __syncthreads();  // the ONLY block barrier: W DMA + all staging drained
  if (t >= ntiles) return;

  const int l15 = l & 15;
  const int lg = l >> 4;          // 0..3
  const int q = l15 & 3;          // cls of this lane's A-row
  const int lcell = l15 >> 2;     // cell (0..3) of this lane's A-row
  const int a0 = lg << 3;         // fragment k-offset: 0,8,16,24

  // ---- K1: ctx = sum_k X_k * M_k (16 rows = 4 cells x 4 cls, bf16 MFMA) ----
  f32x4 c0 = {0.f, 0.f, 0.f, 0.f}, c1 = {0.f, 0.f, 0.f, 0.f};
#pragma unroll
  for (int km = 0; km < 4; ++km) {
    short8 av = (short8)0;
    if (a0 < 24) {
      int dy = (km >> 1) & (q >> 1);
      int dx = km & q & 1;
      av = *(const short8*)&LDS[SOFF + (dy * 5 + lcell + dx) * 24 + a0];
    }
    c0 = __builtin_amdgcn_mfma_f32_16x16x32_bf16(av, mb[2 * km], c0, 0, 0, 0);
    c1 = __builtin_amdgcn_mfma_f32_16x16x32_bf16(av, mb[2 * km + 1], c1, 0, 0, 0);
  }

  // ---- gather everything still needed from F BEFORE ctx overlays it ----
  unsigned int fvp[11];  // packed bf16 pairs of center-pixel F row
  {
    const unsigned int* fp = (const unsigned int*)&LDS[SOFF + lcell * 24];
#pragma unroll
    for (int j = 0; j < 11; ++j) fvp[j] = fp[j];
  }
  const float r4 = b2f(LDS[SOFF + lg * 24 + l15]);                       // residual f4-range
  const float r6 = (l15 < 6) ? b2f(LDS[SOFF + lg * 24 + 16 + l15]) : 0.f; // residual f6-range
  WAVE_LDS_FENCE();  // F reads complete before overwrite

  // ---- ctx transpose into the SAME slot (col=pixel(l15), row=chan) ----
#pragma unroll
  for (int r = 0; r < 4; ++r) {
    LDS[SOFF + l15 * 24 + (lg << 2) + r] = bf16u(c0[r]);
    int ch1 = 16 + (lg << 2) + r;
    if (ch1 < 22) LDS[SOFF + l15 * 24 + ch1] = bf16u(c1[r]);
  }
  if (lg == 0) *(unsigned int*)&LDS[SOFF + l15 * 24 + 22] = 0u;  // pad
  WAVE_LDS_FENCE();

  // ---- gather K2 A-source: ctx row (8 chans at a0) ----
  float cv[8];
  {
    short8 cvb = (short8)0;
    if (a0 < 24) cvb = *(const short8*)&LDS[SOFF + l15 * 24 + a0];
#pragma unroll
    for (int j = 0; j < 8; ++j) cv[j] = (a0 < 24) ? b2f((unsigned short)cvb[j]) : 0.f;
  }

  // ---- K2 (fp8): out = sum_a F[a] * (ctx . W[a]); even/odd dual chains ----
  f32x4 oE0 = {0.f, 0.f, 0.f, 0.f}, oE1 = {0.f, 0.f, 0.f, 0.f};
  f32x4 oO0 = {0.f, 0.f, 0.f, 0.f}, oO1 = {0.f, 0.f, 0.f, 0.f};
  const char* Wb = (const char*)LDS;
#pragma unroll
  for (int ap = 0; ap < 11; ++ap) {
    const float sE = __builtin_bit_cast(float, fvp[ap] << 16);          // even chan
    const float sO = __builtin_bit_cast(float, fvp[ap] & 0xffff0000u);  // odd chan
    {
      const int a = 2 * ap;
      int lo = __builtin_amdgcn_cvt_pk_fp8_f32(cv[0] * sE, cv[1] * sE, 0, 0);
      lo = __builtin_amdgcn_cvt_pk_fp8_f32(cv[2] * sE, cv[3] * sE, lo, 1);
      int hi = __builtin_amdgcn_cvt_pk_fp8_f32(cv[4] * sE, cv[5] * sE, 0, 0);
      hi = __builtin_amdgcn_cvt_pk_fp8_f32(cv[6] * sE, cv[7] * sE, hi, 1);
      long av = (long)(((unsigned long long)(unsigned int)hi << 32) | (unsigned int)lo);
      long w0 = *(const long*)(Wb + a * 1024 + l * 8);
      long w1 = *(const long*)(Wb + a * 1024 + 512 + l * 8);
      oE0 = __builtin_amdgcn_mfma_f32_16x16x32_fp8_fp8(av, w0, oE0, 0, 0, 0);
      oE1 = __builtin_amdgcn_mfma_f32_16x16x32_fp8_fp8(av, w1, oE1, 0, 0, 0);
    }
    {
      const int a = 2 * ap + 1;
      int lo = __builtin_amdgcn_cvt_pk_fp8_f32(cv[0] * sO, cv[1] * sO, 0, 0);
      lo = __builtin_amdgcn_cvt_pk_fp8_f32(cv[2] * sO, cv[3] * sO, lo, 1);
      int hi = __builtin_amdgcn_cvt_pk_fp8_f32(cv[4] * sO, cv[5] * sO, 0, 0);
      hi = __builtin_amdgcn_cvt_pk_fp8_f32(cv[6] * sO, cv[7] * sO, hi, 1);
      long av = (long)(((unsigned long long)(unsigned int)hi << 32) | (unsigned int)lo);
      long w0 = *(const long*)(Wb + a * 1024 + l * 8);
      long w1 = *(const long*)(Wb + a * 1024 + 512 + l * 8);
      oO0 = __builtin_amdgcn_mfma_f32_16x16x32_fp8_fp8(av, w0, oO0, 0, 0, 0);
      oO1 = __builtin_amdgcn_mfma_f32_16x16x32_fp8_fp8(av, w1, oO1, 0, 0, 0);
    }
  }

  // ---- epilogue: vout = out + residual F (overwrites ctx slot) ----
#pragma unroll
  for (int r = 0; r < 4; ++r) {
    int n = (lg << 2) + r;  // pixel row within wave's 16
    LDS[SOFF + n * 24 + l15] = bf16u(oE0[r] + oO0[r] + r4);
    if (l15 < 6) LDS[SOFF + n * 24 + 16 + l15] = bf16u(oE1[r] + oO1[r] + r6);
  }
  WAVE_LDS_FENCE();

  // ---- writer: wave's 4 cells -> HR rows 4*y0..+3, 16 px wide ----
  {
    const int Wr = Wc << 2;
    const long long Npix = (long long)H * Wc * 16;
    float* out6 = out + Npix * 9;
    const int vx = max(min(4, Wc - cw0), 0) << 2;  // valid HR px in this wave
    const long long rb = (long long)(y0 << 2) * Wr + ((long long)cw0 << 2);
#pragma unroll
    for (int s = 0; s < 9; ++s) {
      int idx = s * 64 + l;
      int ry = idx / 144;
      int rem = idx - ry * 144;
      int px = rem / 9;
      if (px < vx) {
        int n = (px & ~3) + ((ry == 3) ? 2 : 0) + (((px & 3) == 3) ? 1 : 0);
        int ch = rem - px * 9;
        out[(rb + (long long)ry * Wr) * 9 + rem] = b2f(LDS[SOFF + n * 24 + ch]);
      }
    }
#pragma unroll
    for (int s = 0; s < 13; ++s) {
      int idx = s * 64 + l;
      int ry = idx / 208;
      int rem = idx - ry * 208;
      int px = rem / 13;
      if (px < vx) {
        int n = (px & ~3) + ((ry == 3) ? 2 : 0) + (((px & 3) == 3) ? 1 : 0);
        int ch = rem - px * 13;
        out6[(rb + (long long)ry * Wr) * 13 + rem] = b2f(LDS[SOFF + n * 24 + 9 + ch]);
      }
    }
  }
}

extern "C" void kernel_launch(void* const* d_in, const int* in_sizes, int n_in,
                              void* d_out, int out_size, void* d_ws, size_t ws_size,
                              hipStream_t stream) {
  const float* f4 = (const float*)d_in[0];
  const float* f6 = (const float*)d_in[1];
  const int* ph = (const int*)d_in[2];
  const int* pw = (const int*)d_in[3];
  const float* wagg = (const float*)d_in[4];
  const float* wtp = (const float*)d_in[5];
  float* out = (float*)d_out;
  unsigned short* wsu = (unsigned short*)d_ws;

  long long HW = (long long)in_sizes[0] / 9;
  long long tail = (long long)out_size - 2;

  eq_setup<<<104, 256, 0, stream>>>(wagg, wtp, ph, pw, out, tail, wsu);

  int S = (int)(sqrt((double)HW) + 0.5);
  long long nb;
  if ((long long)S * S == HW) {
    nb = (long long)((S + 31) / 32) * S;  // square image (the bench case)
  } else {
    nb = HW;  // conservative cover; excess blocks exit after the barrier
  }
  eq_main<<<(int)nb, 512, 0, stream>>>(f4, f6, ph, pw, wsu, out);
}

// Round 7
// 54.635 us; speedup vs baseline: 1.5634x; 1.1550x over previous
//
#include <hip/hip_runtime.h>
#include <hip/hip_bf16.h>
#include <math.h>

typedef __attribute__((ext_vector_type(8))) short short8;
typedef __attribute__((ext_vector_type(4))) float f32x4;
typedef __attribute__((ext_vector_type(2))) float f32x2;

// ---------------- factorial tables (fp32) -------------------------
__constant__ float c_fact[20] = {
    1.0f, 1.0f, 2.0f, 6.0f, 24.0f, 120.0f, 720.0f, 5040.0f, 40320.0f, 362880.0f,
    3628800.0f, 39916800.0f, 479001600.0f, 6227020800.0f, 87178291200.0f,
    1307674368000.0f, 20922789888000.0f, 355687428096000.0f,
    6402373705728000.0f, 121645100408832000.0f};
__constant__ float c_invf[20] = {
    1.0f, 1.0f, 0.5f, 0.16666666666666666f, 0.041666666666666664f,
    0.008333333333333333f, 0.001388888888888889f, 1.984126984126984e-4f,
    2.48015873015873e-5f, 2.755731922398589e-6f, 2.755731922398589e-7f,
    2.505210838544172e-8f, 2.08767569878681e-9f, 1.6059043836821613e-10f,
    1.1470745597729725e-11f, 7.647163731819816e-13f, 4.779477332387385e-14f,
    2.8114572543455206e-15f, 1.5619206968586225e-16f, 8.22063524662433e-18f};

__device__ float cgd(int j1, int m1, int j2, int m2, int j3, int m3) {
  if (m1 + m2 != m3) return 0.0f;
  float pre = (float)(2 * j3 + 1) * c_fact[j1 + j2 - j3] * c_fact[j1 - j2 + j3] *
              c_fact[-j1 + j2 + j3] * c_invf[j1 + j2 + j3 + 1];
  pre *= c_fact[j1 + m1] * c_fact[j1 - m1] * c_fact[j2 + m2] * c_fact[j2 - m2] *
         c_fact[j3 + m3] * c_fact[j3 - m3];
  int kmin = max(0, max(j2 - j3 - m1, j1 - j3 + m2));
  int kmax = min(j1 + j2 - j3, min(j1 - m1, j2 + m2));
  float s = 0.0f;
  for (int k = kmin; k <= kmax; ++k) {
    float d = c_invf[k] * c_invf[j1 + j2 - j3 - k] * c_invf[j1 - m1 - k] *
              c_invf[j2 + m2 - k] * c_invf[j3 - j2 + m1 + k] * c_invf[j3 - j1 - m2 + k];
    s += ((k & 1) ? -d : d);
  }
  return sqrtf(pre) * s;
}

__device__ float wstd(int l1, int l2, int l3, int i, int j, int k) {
  int m1 = i - l1, m2 = j - l2, m3 = k - l3;
  if (m1 + m2 + m3 != 0) return 0.0f;
  int e = l1 - l2 - m3;
  float sgn = (e & 1) ? -1.0f : 1.0f;
  return sgn * (1.0f / sqrtf((float)(2 * l3 + 1))) * cgd(l1, m1, l2, m2, l3, -m3);
}

__device__ int qrow(int l, int a, int idx[2], float vr[2], float vi[2]) {
  const float s2 = 0.70710678118654752440f;
  int m = a - l;
  if (m == 0) { idx[0] = l; vr[0] = 1.0f; vi[0] = 0.0f; return 1; }
  if (m > 0) {
    idx[0] = l + m; vr[0] = (m & 1) ? -s2 : s2; vi[0] = 0.0f;
    idx[1] = l - m; vr[1] = s2;                 vi[1] = 0.0f;
    return 2;
  }
  int mm = -m;
  idx[0] = l - mm; vr[0] = 0.0f; vi[0] = s2;
  idx[1] = l + mm; vr[1] = 0.0f; vi[1] = (mm & 1) ? s2 : -s2;
  return 2;
}

__device__ float w3j_real(int l1, int l2, int l3, int a, int b, int c) {
  int i1[2], i2[2], i3[2];
  float r1[2], s1[2], r2[2], s2v[2], r3[2], s3[2];
  int n1 = qrow(l1, a, i1, r1, s1);
  int n2 = qrow(l2, b, i2, r2, s2v);
  int n3 = qrow(l3, c, i3, r3, s3);
  float re = 0.0f;
  for (int x = 0; x < n1; ++x)
    for (int y = 0; y < n2; ++y)
      for (int z = 0; z < n3; ++z) {
        float w = wstd(l1, l2, l3, i1[x], i2[y], i3[z]);
        if (w == 0.0f) continue;
        float pr = r1[x] * r2[y] - s1[x] * s2v[y];
        float pi = r1[x] * s2v[y] + s1[x] * r2[y];
        float qr = pr * r3[z] - pi * s3[z];
        re += qr * w;
      }
  int L = l1 + l2 + l3;
  return ((L & 3) == 0) ? re : -re;
}

__device__ float sh_val(int k, int col) {
  const float PI_ = 3.14159265358979323846f;
  float sgn = (k == 0 || k == 3) ? 1.0f : -1.0f;
  if (col == 0) return 0.5f / sqrtf(PI_);
  if (col == 1) return sgn * 0.25f * sqrtf(15.0f / PI_);
  if (col == 3) return -0.25f * sqrtf(5.0f / PI_);
  return 0.0f;
}

__device__ __forceinline__ unsigned short bf16u(float x) {
  __hip_bfloat16 h = __float2bfloat16(x);
  return __builtin_bit_cast(unsigned short, h);
}
__device__ __forceinline__ float b2f(unsigned short u) {
  unsigned int v = ((unsigned int)u) << 16;
  return __builtin_bit_cast(float, v);
}

// ws layout: bytes [0, 22528) = W3G fp8 frag-swizzled;
//            ushort offset 11264..15360 = M3G bf16 (4096 ush)
__global__ void eq_setup(const float* __restrict__ w_agg, const float* __restrict__ w_tp,
                         const int* __restrict__ ph, const int* __restrict__ pw,
                         float* __restrict__ out, long long tail_off,
                         unsigned short* __restrict__ ws) {
  int gid = blockIdx.x * 256 + threadIdx.x;
  if (gid == 0) {
    out[tail_off]     = (float)(ph[0] * 4);
    out[tail_off + 1] = (float)(pw[0] * 4);
  }
  if (gid < 22528) {  // W3G: fp8 B-fragment byte for K2
    int a = gid >> 10;
    int rem = gid & 1023;
    int nt = rem >> 9;
    int l = (rem >> 3) & 63;
    int e = rem & 7;
    int b = ((l >> 4) << 3) + e;   // k index (contraction over b)
    int c = nt * 16 + (l & 15);    // output col
    float v = 0.f;
    if (b < 22 && c < 22) {
      int l1 = (a < 9) ? 4 : 6, l2 = (b < 9) ? 4 : 6, l3 = (c < 9) ? 4 : 6;
      int a_ = (a < 9) ? a : a - 9, b_ = (b < 9) ? b : b - 9, c_ = (c < 9) ? c : c - 9;
      int idx = ((l1 == 6) ? 4 : 0) + ((l2 == 6) ? 2 : 0) + ((l3 == 6) ? 1 : 0);
      float alpha = sqrtf((float)(2 * l3 + 1) * 0.25f);
      v = w_tp[idx] * alpha * w3j_real(l1, l2, l3, a_, b_, c_);
    }
    int pk = __builtin_amdgcn_cvt_pk_fp8_f32(v, 0.f, 0, 0);
    ((unsigned char*)ws)[gid] = (unsigned char)(pk & 0xff);
  } else if (gid < 26624) {  // M3G: bf16 B-fragment element for K1
    int s = gid - 22528;
    int km = s >> 10;
    int rem = s & 1023;
    int nt = rem >> 9;
    int l = (rem >> 3) & 63;
    int e = rem & 7;
    int a = ((l >> 4) << 3) + e;   // k index (contraction over a)
    int c = nt * 16 + (l & 15);    // output col
    float v = 0.f;
    if (a < 22 && c < 22) {
      int l1 = (a < 9) ? 4 : 6, l3 = (c < 9) ? 4 : 6;
      int a_ = (a < 9) ? a : a - 9, c_ = (c < 9) ? c : c - 9;
      float acc = 0.0f;
      float alpha = sqrtf((float)(2 * l3 + 1) / 3.0f);
      if (l1 == l3) {
        int i = (l1 == 4) ? 0 : 3;
        acc += w_agg[i] * alpha * sh_val(km, 0) * w3j_real(l1, 0, l3, a_, 0, c_);
      }
      {
        int i = (l1 == 4) ? ((l3 == 4) ? 1 : 2) : ((l3 == 4) ? 4 : 5);
        float t = 0.0f;
        for (int bb = 0; bb < 5; ++bb) {
          float shv = sh_val(km, 1 + bb);
          if (shv != 0.0f) t += shv * w3j_real(l1, 2, l3, a_, bb, c_);
        }
        acc += w_agg[i] * alpha * t;
      }
      v = acc;
    }
    ws[11264 + s] = bf16u(v);
  }
}

__device__ __forceinline__ void load_lds16(const unsigned int* g, unsigned int* l) {
  __builtin_amdgcn_global_load_lds(
      (const __attribute__((address_space(1))) unsigned int*)g,
      (__attribute__((address_space(3))) unsigned int*)l, 16, 0, 0);
}

#define WAVE_LDS_FENCE() do { \
    asm volatile("s_waitcnt lgkmcnt(0)" ::: "memory"); \
    __builtin_amdgcn_sched_barrier(0); } while (0)

// ------- main kernel: 32 cells/block, 512 threads; each WAVE owns 4 cells,
// ------- one block barrier; fp8 W table; per-wave 512-ush overlaid scratch -------
__global__ __launch_bounds__(512, 8) void eq_main(
    const float* __restrict__ f4, const float* __restrict__ f6,
    const int* __restrict__ ph, const int* __restrict__ pw,
    const unsigned short* __restrict__ ws, float* __restrict__ out) {
  const int H = ph[0], Wc = pw[0];
  const int bx = (Wc + 31) >> 5;
  const long long ntiles = (long long)bx * H;

  // LDS (ushort units): W fp8 [0, 11264); per-wave scratch 512 ush at 11264+wv*512:
  //   F region  [SOFF, SOFF+240): 10 px x 24 ch bf16   (phase 1)
  //   ctx/vout  [SOFF, SOFF+384): 16 rows x 24 ch bf16 (phases 2+, overlays F)
  __shared__ __align__(16) unsigned short LDS[15360];  // 30720 B

  const int tid = threadIdx.x;
  const int wv = tid >> 6;
  const int l = tid & 63;
  const long long t = blockIdx.x;

  // ---- stage W table via async global->LDS DMA (22 KiB, linear) ----
  {
    const unsigned int* src = (const unsigned int*)ws;
    unsigned int* dst = (unsigned int*)LDS;
#pragma unroll
    for (int i = 0; i < 3; ++i) {
      int chunk = i * 8 + wv;  // wave-uniform; 1 KiB per chunk
      if (chunk < 22) load_lds16(src + chunk * 256 + l * 4, dst + chunk * 256);
    }
  }

  // ---- K1 M-fragments straight from global (L2-hot, bf16) ----
  short8 mb[8];
  {
    const short8* msrc = (const short8*)(ws + 11264);
#pragma unroll
    for (int i = 0; i < 8; ++i) mb[i] = msrc[i * 64 + l];
  }

  // ---- per-wave feature staging: 2 rows x 5 cols x 22 ch -> bf16 LDS ----
  const int y0 = (int)(t / bx);
  const int xC0 = (int)(t - (long long)y0 * bx) << 5;
  const int cw0 = xC0 + (wv << 2);          // this wave's first coarse cell col
  const int SOFF = 11264 + (wv << 9);       // 512-ush scratch slot
#pragma unroll
  for (int k = 0; k < 2; ++k) {
    int e = k * 64 + l;
    if (e < 110) {
      int px = e / 11, pr = e - px * 11;
      int dyR = px / 5, col = px - dyR * 5;
      int yy = min(y0 + dyR, H - 1);
      int xx = min(cw0 + col, Wc - 1);
      long long p = (long long)yy * Wc + xx;
      int ca = 2 * pr, cb = ca + 1;
      float v0 = (ca < 9) ? f4[p * 9 + ca] : f6[p * 13 + ca - 9];
      float v1 = (cb < 9) ? f4[p * 9 + cb] : f6[p * 13 + cb - 9];
      unsigned int pk = (unsigned int)bf16u(v0) | ((unsigned int)bf16u(v1) << 16);
      *(unsigned int*)&LDS[SOFF + px * 24 + ca] = pk;
    } else if (e < 120) {
      int px = e - 110;
      *(unsigned int*)&LDS[SOFF + px * 24 + 22] = 0u;  // pad chans 22,23
    }
  }

  __syncthreads();  // the ONLY block barrier: W DMA + all staging drained
  if (t >= ntiles) return;

  const int l15 = l & 15;
  const int lg = l >> 4;          // 0..3
  const int q = l15 & 3;          // cls of this lane's A-row
  const int lcell = l15 >> 2;     // cell (0..3) of this lane's A-row
  const int a0 = lg << 3;         // fragment k-offset: 0,8,16,24

  // ---- K1: ctx = sum_k X_k * M_k (16 rows = 4 cells x 4 cls, bf16 MFMA) ----
  f32x4 c0 = {0.f, 0.f, 0.f, 0.f}, c1 = {0.f, 0.f, 0.f, 0.f};
#pragma unroll
  for (int km = 0; km < 4; ++km) {
    short8 av = (short8)0;
    if (a0 < 24) {
      int dy = (km >> 1) & (q >> 1);
      int dx = km & q & 1;
      av = *(const short8*)&LDS[SOFF + (dy * 5 + lcell + dx) * 24 + a0];
    }
    c0 = __builtin_amdgcn_mfma_f32_16x16x32_bf16(av, mb[2 * km], c0, 0, 0, 0);
    c1 = __builtin_amdgcn_mfma_f32_16x16x32_bf16(av, mb[2 * km + 1], c1, 0, 0, 0);
  }

  // ---- gather everything still needed from F BEFORE ctx overlays it ----
  unsigned int fvp[11];  // packed bf16 pairs of center-pixel F row
  {
    const unsigned int* fp = (const unsigned int*)&LDS[SOFF + lcell * 24];
#pragma unroll
    for (int j = 0; j < 11; ++j) fvp[j] = fp[j];
  }
  const float r4 = b2f(LDS[SOFF + lg * 24 + l15]);                        // residual f4-range
  const float r6 = (l15 < 6) ? b2f(LDS[SOFF + lg * 24 + 16 + l15]) : 0.f; // residual f6-range
  WAVE_LDS_FENCE();  // F reads complete before overwrite

  // ---- ctx transpose into the SAME slot (col=pixel(l15), row=chan) ----
#pragma unroll
  for (int r = 0; r < 4; ++r) {
    LDS[SOFF + l15 * 24 + (lg << 2) + r] = bf16u(c0[r]);
    int ch1 = 16 + (lg << 2) + r;
    if (ch1 < 22) LDS[SOFF + l15 * 24 + ch1] = bf16u(c1[r]);
  }
  if (lg == 0) *(unsigned int*)&LDS[SOFF + l15 * 24 + 22] = 0u;  // pad
  WAVE_LDS_FENCE();

  // ---- gather K2 A-source: ctx row (8 chans at a0) as float2 pairs ----
  f32x2 cv2[4];
  {
    short8 cvb = (short8)0;
    if (a0 < 24) cvb = *(const short8*)&LDS[SOFF + l15 * 24 + a0];
#pragma unroll
    for (int j = 0; j < 4; ++j) {
      cv2[j][0] = b2f((unsigned short)cvb[2 * j]);
      cv2[j][1] = b2f((unsigned short)cvb[2 * j + 1]);
    }
  }

  // ---- K2 (fp8): out = sum_a F[a] * (ctx . W[a]); even/odd dual chains ----
  f32x4 oE0 = {0.f, 0.f, 0.f, 0.f}, oE1 = {0.f, 0.f, 0.f, 0.f};
  f32x4 oO0 = {0.f, 0.f, 0.f, 0.f}, oO1 = {0.f, 0.f, 0.f, 0.f};
  const char* Wb = (const char*)LDS;
#pragma unroll
  for (int ap = 0; ap < 11; ++ap) {
    const float sE = __builtin_bit_cast(float, fvp[ap] << 16);          // even chan
    const float sO = __builtin_bit_cast(float, fvp[ap] & 0xffff0000u);  // odd chan
    {
      const f32x2 s2 = {sE, sE};
      f32x2 p0 = cv2[0] * s2, p1 = cv2[1] * s2, p2 = cv2[2] * s2, p3 = cv2[3] * s2;
      int lo = __builtin_amdgcn_cvt_pk_fp8_f32(p0[0], p0[1], 0, 0);
      lo = __builtin_amdgcn_cvt_pk_fp8_f32(p1[0], p1[1], lo, 1);
      int hi = __builtin_amdgcn_cvt_pk_fp8_f32(p2[0], p2[1], 0, 0);
      hi = __builtin_amdgcn_cvt_pk_fp8_f32(p3[0], p3[1], hi, 1);
      long av = (long)(((unsigned long long)(unsigned int)hi << 32) | (unsigned int)lo);
      long w0 = *(const long*)(Wb + ap * 2048 + l * 8);
      long w1 = *(const long*)(Wb + ap * 2048 + 512 + l * 8);
      oE0 = __builtin_amdgcn_mfma_f32_16x16x32_fp8_fp8(av, w0, oE0, 0, 0, 0);
      oE1 = __builtin_amdgcn_mfma_f32_16x16x32_fp8_fp8(av, w1, oE1, 0, 0, 0);
    }
    {
      const f32x2 s2 = {sO, sO};
      f32x2 p0 = cv2[0] * s2, p1 = cv2[1] * s2, p2 = cv2[2] * s2, p3 = cv2[3] * s2;
      int lo = __builtin_amdgcn_cvt_pk_fp8_f32(p0[0], p0[1], 0, 0);
      lo = __builtin_amdgcn_cvt_pk_fp8_f32(p1[0], p1[1], lo, 1);
      int hi = __builtin_amdgcn_cvt_pk_fp8_f32(p2[0], p2[1], 0, 0);
      hi = __builtin_amdgcn_cvt_pk_fp8_f32(p3[0], p3[1], hi, 1);
      long av = (long)(((unsigned long long)(unsigned int)hi << 32) | (unsigned int)lo);
      long w0 = *(const long*)(Wb + ap * 2048 + 1024 + l * 8);
      long w1 = *(const long*)(Wb + ap * 2048 + 1536 + l * 8);
      oO0 = __builtin_amdgcn_mfma_f32_16x16x32_fp8_fp8(av, w0, oO0, 0, 0, 0);
      oO1 = __builtin_amdgcn_mfma_f32_16x16x32_fp8_fp8(av, w1, oO1, 0, 0, 0);
    }
  }

  // ---- epilogue: vout = out + residual F (overwrites ctx slot) ----
#pragma unroll
  for (int r = 0; r < 4; ++r) {
    int n = (lg << 2) + r;  // pixel row within wave's 16
    LDS[SOFF + n * 24 + l15] = bf16u(oE0[r] + oO0[r] + r4);
    if (l15 < 6) LDS[SOFF + n * 24 + 16 + l15] = bf16u(oE1[r] + oO1[r] + r6);
  }
  WAVE_LDS_FENCE();

  // ---- writer: lane = (ry, px). 3x ds_read_b128 row fetch, imm-offset stores ----
  {
    const int Wr = Wc << 2;
    const long long Npix = (long long)H * Wc * 16;
    float* out6 = out + Npix * 9;
    const int px = l & 15;     // HR px within wave's 16
    const int ry = l >> 2 >> 2;  // HR row 0..3 (l>>4)
    const int n = (px & ~3) | ((ry == 3) ? 2 : 0) | (((px & 3) == 3) ? 1 : 0);
    const short8 r0 = *(const short8*)&LDS[SOFF + n * 24];
    const short8 r1 = *(const short8*)&LDS[SOFF + n * 24 + 8];
    const short8 r2 = *(const short8*)&LDS[SOFF + n * 24 + 16];
    const int hrx = (cw0 << 2) + px;
    if (hrx < Wr) {
      const long long rowb = (long long)((y0 << 2) + ry) * Wr + hrx;
      float* o4 = out + rowb * 9;
#pragma unroll
      for (int j = 0; j < 8; ++j) o4[j] = b2f((unsigned short)r0[j]);
      o4[8] = b2f((unsigned short)r1[0]);
      float* o6 = out6 + rowb * 13;
#pragma unroll
      for (int j = 0; j < 7; ++j) o6[j] = b2f((unsigned short)r1[1 + j]);
#pragma unroll
      for (int j = 0; j < 6; ++j) o6[7 + j] = b2f((unsigned short)r2[j]);
    }
  }
}

extern "C" void kernel_launch(void* const* d_in, const int* in_sizes, int n_in,
                              void* d_out, int out_size, void* d_ws, size_t ws_size,
                              hipStream_t stream) {
  const float* f4 = (const float*)d_in[0];
  const float* f6 = (const float*)d_in[1];
  const int* ph = (const int*)d_in[2];
  const int* pw = (const int*)d_in[3];
  const float* wagg = (const float*)d_in[4];
  const float* wtp = (const float*)d_in[5];
  float* out = (float*)d_out;
  unsigned short* wsu = (unsigned short*)d_ws;

  long long HW = (long long)in_sizes[0] / 9;
  long long tail = (long long)out_size - 2;

  eq_setup<<<104, 256, 0, stream>>>(wagg, wtp, ph, pw, out, tail, wsu);

  int S = (int)(sqrt((double)HW) + 0.5);
  long long nb;
  if ((long long)S * S == HW) {
    nb = (long long)((S + 31) / 32) * S;  // square image (the bench case)
  } else {
    nb = HW;  // conservative cover; excess blocks exit after the barrier
  }
  eq_main<<<(int)nb, 512, 0, stream>>>(f4, f6, ph, pw, wsu, out);
}

// Round 8
// 53.861 us; speedup vs baseline: 1.5858x; 1.0144x over previous
//
#include <hip/hip_runtime.h>
#include <hip/hip_bf16.h>
#include <math.h>

typedef __attribute__((ext_vector_type(8))) short short8;
typedef __attribute__((ext_vector_type(4))) float f32x4;
typedef __attribute__((ext_vector_type(2))) float f32x2;

// ---------------- factorial tables (fp32) -------------------------
__constant__ float c_fact[20] = {
    1.0f, 1.0f, 2.0f, 6.0f, 24.0f, 120.0f, 720.0f, 5040.0f, 40320.0f, 362880.0f,
    3628800.0f, 39916800.0f, 479001600.0f, 6227020800.0f, 87178291200.0f,
    1307674368000.0f, 20922789888000.0f, 355687428096000.0f,
    6402373705728000.0f, 121645100408832000.0f};
__constant__ float c_invf[20] = {
    1.0f, 1.0f, 0.5f, 0.16666666666666666f, 0.041666666666666664f,
    0.008333333333333333f, 0.001388888888888889f, 1.984126984126984e-4f,
    2.48015873015873e-5f, 2.755731922398589e-6f, 2.755731922398589e-7f,
    2.505210838544172e-8f, 2.08767569878681e-9f, 1.6059043836821613e-10f,
    1.1470745597729725e-11f, 7.647163731819816e-13f, 4.779477332387385e-14f,
    2.8114572543455206e-15f, 1.5619206968586225e-16f, 8.22063524662433e-18f};

__device__ float cgd(int j1, int m1, int j2, int m2, int j3, int m3) {
  if (m1 + m2 != m3) return 0.0f;
  float pre = (float)(2 * j3 + 1) * c_fact[j1 + j2 - j3] * c_fact[j1 - j2 + j3] *
              c_fact[-j1 + j2 + j3] * c_invf[j1 + j2 + j3 + 1];
  pre *= c_fact[j1 + m1] * c_fact[j1 - m1] * c_fact[j2 + m2] * c_fact[j2 - m2] *
         c_fact[j3 + m3] * c_fact[j3 - m3];
  int kmin = max(0, max(j2 - j3 - m1, j1 - j3 + m2));
  int kmax = min(j1 + j2 - j3, min(j1 - m1, j2 + m2));
  float s = 0.0f;
  for (int k = kmin; k <= kmax; ++k) {
    float d = c_invf[k] * c_invf[j1 + j2 - j3 - k] * c_invf[j1 - m1 - k] *
              c_invf[j2 + m2 - k] * c_invf[j3 - j2 + m1 + k] * c_invf[j3 - j1 - m2 + k];
    s += ((k & 1) ? -d : d);
  }
  return sqrtf(pre) * s;
}

__device__ float wstd(int l1, int l2, int l3, int i, int j, int k) {
  int m1 = i - l1, m2 = j - l2, m3 = k - l3;
  if (m1 + m2 + m3 != 0) return 0.0f;
  int e = l1 - l2 - m3;
  float sgn = (e & 1) ? -1.0f : 1.0f;
  return sgn * (1.0f / sqrtf((float)(2 * l3 + 1))) * cgd(l1, m1, l2, m2, l3, -m3);
}

__device__ int qrow(int l, int a, int idx[2], float vr[2], float vi[2]) {
  const float s2 = 0.70710678118654752440f;
  int m = a - l;
  if (m == 0) { idx[0] = l; vr[0] = 1.0f; vi[0] = 0.0f; return 1; }
  if (m > 0) {
    idx[0] = l + m; vr[0] = (m & 1) ? -s2 : s2; vi[0] = 0.0f;
    idx[1] = l - m; vr[1] = s2;                 vi[1] = 0.0f;
    return 2;
  }
  int mm = -m;
  idx[0] = l - mm; vr[0] = 0.0f; vi[0] = s2;
  idx[1] = l + mm; vr[1] = 0.0f; vi[1] = (mm & 1) ? s2 : -s2;
  return 2;
}

__device__ float w3j_real(int l1, int l2, int l3, int a, int b, int c) {
  int i1[2], i2[2], i3[2];
  float r1[2], s1[2], r2[2], s2v[2], r3[2], s3[2];
  int n1 = qrow(l1, a, i1, r1, s1);
  int n2 = qrow(l2, b, i2, r2, s2v);
  int n3 = qrow(l3, c, i3, r3, s3);
  float re = 0.0f;
  for (int x = 0; x < n1; ++x)
    for (int y = 0; y < n2; ++y)
      for (int z = 0; z < n3; ++z) {
        float w = wstd(l1, l2, l3, i1[x], i2[y], i3[z]);
        if (w == 0.0f) continue;
        float pr = r1[x] * r2[y] - s1[x] * s2v[y];
        float pi = r1[x] * s2v[y] + s1[x] * r2[y];
        float qr = pr * r3[z] - pi * s3[z];
        re += qr * w;
      }
  int L = l1 + l2 + l3;
  return ((L & 3) == 0) ? re : -re;
}

__device__ float sh_val(int k, int col) {
  const float PI_ = 3.14159265358979323846f;
  float sgn = (k == 0 || k == 3) ? 1.0f : -1.0f;
  if (col == 0) return 0.5f / sqrtf(PI_);
  if (col == 1) return sgn * 0.25f * sqrtf(15.0f / PI_);
  if (col == 3) return -0.25f * sqrtf(5.0f / PI_);
  return 0.0f;
}

__device__ __forceinline__ unsigned short bf16u(float x) {
  __hip_bfloat16 h = __float2bfloat16(x);
  return __builtin_bit_cast(unsigned short, h);
}
__device__ __forceinline__ float b2f(unsigned short u) {
  unsigned int v = ((unsigned int)u) << 16;
  return __builtin_bit_cast(float, v);
}

// ws layout: bytes [0, 22528) = W3G fp8 frag-swizzled;
//            ushort offset 11264..15360 = M3G bf16 (4096 ush)
__global__ void eq_setup(const float* __restrict__ w_agg, const float* __restrict__ w_tp,
                         const int* __restrict__ ph, const int* __restrict__ pw,
                         float* __restrict__ out, long long tail_off,
                         unsigned short* __restrict__ ws) {
  int gid = blockIdx.x * 256 + threadIdx.x;
  if (gid == 0) {
    out[tail_off]     = (float)(ph[0] * 4);
    out[tail_off + 1] = (float)(pw[0] * 4);
  }
  if (gid < 22528) {  // W3G: fp8 B-fragment byte for K2
    int a = gid >> 10;
    int rem = gid & 1023;
    int nt = rem >> 9;
    int l = (rem >> 3) & 63;
    int e = rem & 7;
    int b = ((l >> 4) << 3) + e;   // k index (contraction over b)
    int c = nt * 16 + (l & 15);    // output col
    float v = 0.f;
    if (b < 22 && c < 22) {
      int l1 = (a < 9) ? 4 : 6, l2 = (b < 9) ? 4 : 6, l3 = (c < 9) ? 4 : 6;
      int a_ = (a < 9) ? a : a - 9, b_ = (b < 9) ? b : b - 9, c_ = (c < 9) ? c : c - 9;
      int idx = ((l1 == 6) ? 4 : 0) + ((l2 == 6) ? 2 : 0) + ((l3 == 6) ? 1 : 0);
      float alpha = sqrtf((float)(2 * l3 + 1) * 0.25f);
      v = w_tp[idx] * alpha * w3j_real(l1, l2, l3, a_, b_, c_);
    }
    int pk = __builtin_amdgcn_cvt_pk_fp8_f32(v, 0.f, 0, 0);
    ((unsigned char*)ws)[gid] = (unsigned char)(pk & 0xff);
  } else if (gid < 26624) {  // M3G: bf16 B-fragment element for K1
    int s = gid - 22528;
    int km = s >> 10;
    int rem = s & 1023;
    int nt = rem >> 9;
    int l = (rem >> 3) & 63;
    int e = rem & 7;
    int a = ((l >> 4) << 3) + e;   // k index (contraction over a)
    int c = nt * 16 + (l & 15);    // output col
    float v = 0.f;
    if (a < 22 && c < 22) {
      int l1 = (a < 9) ? 4 : 6, l3 = (c < 9) ? 4 : 6;
      int a_ = (a < 9) ? a : a - 9, c_ = (c < 9) ? c : c - 9;
      float acc = 0.0f;
      float alpha = sqrtf((float)(2 * l3 + 1) / 3.0f);
      if (l1 == l3) {
        int i = (l1 == 4) ? 0 : 3;
        acc += w_agg[i] * alpha * sh_val(km, 0) * w3j_real(l1, 0, l3, a_, 0, c_);
      }
      {
        int i = (l1 == 4) ? ((l3 == 4) ? 1 : 2) : ((l3 == 4) ? 4 : 5);
        float t = 0.0f;
        for (int bb = 0; bb < 5; ++bb) {
          float shv = sh_val(km, 1 + bb);
          if (shv != 0.0f) t += shv * w3j_real(l1, 2, l3, a_, bb, c_);
        }
        acc += w_agg[i] * alpha * t;
      }
      v = acc;
    }
    ws[11264 + s] = bf16u(v);
  }
}

__device__ __forceinline__ void load_lds16(const unsigned int* g, unsigned int* l) {
  __builtin_amdgcn_global_load_lds(
      (const __attribute__((address_space(1))) unsigned int*)g,
      (__attribute__((address_space(3))) unsigned int*)l, 16, 0, 0);
}

#define WAVE_LDS_FENCE() do { \
    asm volatile("s_waitcnt lgkmcnt(0)" ::: "memory"); \
    __builtin_amdgcn_sched_barrier(0); } while (0)

// K1->epilogue for one tile (wave-local; LDS W at 0, M at 11264, F at SOFF, ctx at COFF)
__device__ __forceinline__ void compute_phase(
    unsigned short* LDS, int SOFF, int COFF,
    int l, int l15, int lg, int q, int lcell, int a0) {
  // ---- K1 M-fragments from LDS ----
  short8 mb[8];
#pragma unroll
  for (int i = 0; i < 8; ++i) mb[i] = *(const short8*)&LDS[11264 + i * 512 + l * 8];

  // ---- K1: ctx = sum_k X_k * M_k ----
  f32x4 c0 = {0.f, 0.f, 0.f, 0.f}, c1 = {0.f, 0.f, 0.f, 0.f};
#pragma unroll
  for (int km = 0; km < 4; ++km) {
    short8 av = (short8)0;
    if (a0 < 24) {
      int dy = (km >> 1) & (q >> 1);
      int dx = km & q & 1;
      av = *(const short8*)&LDS[SOFF + (dy * 5 + lcell + dx) * 24 + a0];
    }
    c0 = __builtin_amdgcn_mfma_f32_16x16x32_bf16(av, mb[2 * km], c0, 0, 0, 0);
    c1 = __builtin_amdgcn_mfma_f32_16x16x32_bf16(av, mb[2 * km + 1], c1, 0, 0, 0);
  }

  // ---- gather F-dependent values ----
  unsigned int fvp[11];  // packed bf16 pairs of center-pixel F row
  {
    const unsigned int* fp = (const unsigned int*)&LDS[SOFF + lcell * 24];
#pragma unroll
    for (int j = 0; j < 11; ++j) fvp[j] = fp[j];
  }
  const float r4 = b2f(LDS[SOFF + lg * 24 + l15]);
  const float r6 = (l15 < 6) ? b2f(LDS[SOFF + lg * 24 + 16 + l15]) : 0.f;
  WAVE_LDS_FENCE();

  // ---- ctx transpose into COFF (col=pixel(l15), row=chan) ----
#pragma unroll
  for (int r = 0; r < 4; ++r) {
    LDS[COFF + l15 * 24 + (lg << 2) + r] = bf16u(c0[r]);
    int ch1 = 16 + (lg << 2) + r;
    if (ch1 < 22) LDS[COFF + l15 * 24 + ch1] = bf16u(c1[r]);
  }
  if (lg == 0) *(unsigned int*)&LDS[COFF + l15 * 24 + 22] = 0u;  // pad
  WAVE_LDS_FENCE();

  // ---- K2 A-source: ctx row (8 chans at a0) as float2 pairs ----
  f32x2 cv2[4];
  {
    short8 cvb = (short8)0;
    if (a0 < 24) cvb = *(const short8*)&LDS[COFF + l15 * 24 + a0];
#pragma unroll
    for (int j = 0; j < 4; ++j) {
      cv2[j][0] = b2f((unsigned short)cvb[2 * j]);
      cv2[j][1] = b2f((unsigned short)cvb[2 * j + 1]);
    }
  }

  // ---- K2 (fp8): out = sum_a F[a] * (ctx . W[a]); even/odd dual chains ----
  f32x4 oE0 = {0.f, 0.f, 0.f, 0.f}, oE1 = {0.f, 0.f, 0.f, 0.f};
  f32x4 oO0 = {0.f, 0.f, 0.f, 0.f}, oO1 = {0.f, 0.f, 0.f, 0.f};
  const char* Wb = (const char*)LDS;
#pragma unroll
  for (int ap = 0; ap < 11; ++ap) {
    const float sE = __builtin_bit_cast(float, fvp[ap] << 16);
    const float sO = __builtin_bit_cast(float, fvp[ap] & 0xffff0000u);
    {
      const f32x2 s2 = {sE, sE};
      f32x2 p0 = cv2[0] * s2, p1 = cv2[1] * s2, p2 = cv2[2] * s2, p3 = cv2[3] * s2;
      int lo = __builtin_amdgcn_cvt_pk_fp8_f32(p0[0], p0[1], 0, 0);
      lo = __builtin_amdgcn_cvt_pk_fp8_f32(p1[0], p1[1], lo, 1);
      int hi = __builtin_amdgcn_cvt_pk_fp8_f32(p2[0], p2[1], 0, 0);
      hi = __builtin_amdgcn_cvt_pk_fp8_f32(p3[0], p3[1], hi, 1);
      long av = (long)(((unsigned long long)(unsigned int)hi << 32) | (unsigned int)lo);
      long w0 = *(const long*)(Wb + ap * 2048 + l * 8);
      long w1 = *(const long*)(Wb + ap * 2048 + 512 + l * 8);
      oE0 = __builtin_amdgcn_mfma_f32_16x16x32_fp8_fp8(av, w0, oE0, 0, 0, 0);
      oE1 = __builtin_amdgcn_mfma_f32_16x16x32_fp8_fp8(av, w1, oE1, 0, 0, 0);
    }
    {
      const f32x2 s2 = {sO, sO};
      f32x2 p0 = cv2[0] * s2, p1 = cv2[1] * s2, p2 = cv2[2] * s2, p3 = cv2[3] * s2;
      int lo = __builtin_amdgcn_cvt_pk_fp8_f32(p0[0], p0[1], 0, 0);
      lo = __builtin_amdgcn_cvt_pk_fp8_f32(p1[0], p1[1], lo, 1);
      int hi = __builtin_amdgcn_cvt_pk_fp8_f32(p2[0], p2[1], 0, 0);
      hi = __builtin_amdgcn_cvt_pk_fp8_f32(p3[0], p3[1], hi, 1);
      long av = (long)(((unsigned long long)(unsigned int)hi << 32) | (unsigned int)lo);
      long w0 = *(const long*)(Wb + ap * 2048 + 1024 + l * 8);
      long w1 = *(const long*)(Wb + ap * 2048 + 1536 + l * 8);
      oO0 = __builtin_amdgcn_mfma_f32_16x16x32_fp8_fp8(av, w0, oO0, 0, 0, 0);
      oO1 = __builtin_amdgcn_mfma_f32_16x16x32_fp8_fp8(av, w1, oO1, 0, 0, 0);
    }
  }

  // ---- epilogue: vout = out + residual F (into COFF) ----
#pragma unroll
  for (int r = 0; r < 4; ++r) {
    int n = (lg << 2) + r;
    LDS[COFF + n * 24 + l15] = bf16u(oE0[r] + oO0[r] + r4);
    if (l15 < 6) LDS[COFF + n * 24 + 16 + l15] = bf16u(oE1[r] + oO1[r] + r6);
  }
  WAVE_LDS_FENCE();
}

// writer: lane = (ry, px); 3x ds_read row fetch + imm-offset dword stores
__device__ __forceinline__ void writer_phase(
    const unsigned short* LDS, int COFF, int l,
    int y0, int cw0, int Wr, float* out, float* out6) {
  const int px = l & 15;
  const int ry = l >> 4;
  const int n = (px & ~3) | ((ry == 3) ? 2 : 0) | (((px & 3) == 3) ? 1 : 0);
  const short8 r0 = *(const short8*)&LDS[COFF + n * 24];
  const short8 r1 = *(const short8*)&LDS[COFF + n * 24 + 8];
  const short8 r2 = *(const short8*)&LDS[COFF + n * 24 + 16];
  const int hrx = (cw0 << 2) + px;
  if (hrx < Wr) {
    const long long rowb = (long long)((y0 << 2) + ry) * Wr + hrx;
    float* o4 = out + rowb * 9;
#pragma unroll
    for (int j = 0; j < 8; ++j) o4[j] = b2f((unsigned short)r0[j]);
    o4[8] = b2f((unsigned short)r1[0]);
    float* o6 = out6 + rowb * 13;
#pragma unroll
    for (int j = 0; j < 7; ++j) o6[j] = b2f((unsigned short)r1[1 + j]);
#pragma unroll
    for (int j = 0; j < 6; ++j) o6[7 + j] = b2f((unsigned short)r2[j]);
  }
}

// ------- main kernel: TWO 32-cell tiles per block, 512 threads, one barrier -------
__global__ __launch_bounds__(512, 8) void eq_main(
    const float* __restrict__ f4, const float* __restrict__ f6,
    const int* __restrict__ ph, const int* __restrict__ pw,
    const unsigned short* __restrict__ ws, float* __restrict__ out) {
  const int H = ph[0], Wc = pw[0];
  const int bx = (Wc + 31) >> 5;
  const long long ntiles = (long long)bx * H;
  const int Wr = Wc << 2;
  const long long Npix = (long long)H * Wc * 16;
  float* out6 = out + Npix * 9;

  // LDS (ushort units): W fp8 [0,11264); M bf16 [11264,15360);
  // per-wave scratch 640 ush at 15360+wv*640: F [0,240), ctx/vout [256,640)
  __shared__ __align__(16) unsigned short LDS[20480];  // 40960 B

  const int tid = threadIdx.x;
  const int wv = tid >> 6;
  const int l = tid & 63;
  const long long t0 = (long long)blockIdx.x * 2;
  const long long t1 = t0 + 1;
  const bool t0ok = t0 < ntiles;
  const bool t1ok = t1 < ntiles;

  // ---- stage W+M tables via async global->LDS DMA (30 KiB, linear) ----
  {
    const unsigned int* src = (const unsigned int*)ws;
    unsigned int* dst = (unsigned int*)LDS;
#pragma unroll
    for (int i = 0; i < 4; ++i) {
      int chunk = i * 8 + wv;  // wave-uniform; 1 KiB per chunk
      if (chunk < 30) load_lds16(src + chunk * 256 + l * 4, dst + chunk * 256);
    }
  }

  const int SOFF = 15360 + wv * 640;
  const int COFF = SOFF + 256;

  // ---- stage F(tile0) ----
  int y0 = 0, cw0 = 0;
  if (t0ok) {
    y0 = (int)(t0 / bx);
    cw0 = ((int)(t0 - (long long)y0 * bx) << 5) + (wv << 2);
#pragma unroll
    for (int k = 0; k < 2; ++k) {
      int e = k * 64 + l;
      if (e < 110) {
        int px = e / 11, pr = e - px * 11;
        int dyR = px / 5, col = px - dyR * 5;
        int yy = min(y0 + dyR, H - 1);
        int xx = min(cw0 + col, Wc - 1);
        long long p = (long long)yy * Wc + xx;
        int ca = 2 * pr;
        float v0 = (ca < 9) ? f4[p * 9 + ca] : f6[p * 13 + ca - 9];
        float v1 = (ca + 1 < 9) ? f4[p * 9 + ca + 1] : f6[p * 13 + ca - 8];
        unsigned int pk = (unsigned int)bf16u(v0) | ((unsigned int)bf16u(v1) << 16);
        *(unsigned int*)&LDS[SOFF + px * 24 + ca] = pk;
      } else if (e < 120) {
        *(unsigned int*)&LDS[SOFF + (e - 110) * 24 + 22] = 0u;
      }
    }
  }
  __syncthreads();  // the ONLY block barrier (W/M DMA + F staging drained)

  const int l15 = l & 15;
  const int lg = l >> 4;
  const int q = l15 & 3;
  const int lcell = l15 >> 2;
  const int a0 = lg << 3;

  // tile-1 coordinates
  int y1 = 0, cw1 = 0;
  if (t1ok) {
    y1 = (int)(t1 / bx);
    cw1 = ((int)(t1 - (long long)y1 * bx) << 5) + (wv << 2);
  }

  // ================= tile 0 =================
  if (t0ok) {
    compute_phase(LDS, SOFF, COFF, l, l15, lg, q, lcell, a0);

    // ---- issue tile-1 F loads (latency hides under tile-0 writer) ----
    float s_v0_0 = 0.f, s_v1_0 = 0.f, s_v0_1 = 0.f, s_v1_1 = 0.f;
    if (t1ok) {
      {
        int e = l;
        if (e < 110) {
          int px = e / 11, pr = e - px * 11;
          int dyR = px / 5, col = px - dyR * 5;
          int yy = min(y1 + dyR, H - 1);
          int xx = min(cw1 + col, Wc - 1);
          long long p = (long long)yy * Wc + xx;
          int ca = 2 * pr;
          s_v0_0 = (ca < 9) ? f4[p * 9 + ca] : f6[p * 13 + ca - 9];
          s_v1_0 = (ca + 1 < 9) ? f4[p * 9 + ca + 1] : f6[p * 13 + ca - 8];
        }
      }
      {
        int e = 64 + l;
        if (e < 110) {
          int px = e / 11, pr = e - px * 11;
          int dyR = px / 5, col = px - dyR * 5;
          int yy = min(y1 + dyR, H - 1);
          int xx = min(cw1 + col, Wc - 1);
          long long p = (long long)yy * Wc + xx;
          int ca = 2 * pr;
          s_v0_1 = (ca < 9) ? f4[p * 9 + ca] : f6[p * 13 + ca - 9];
          s_v1_1 = (ca + 1 < 9) ? f4[p * 9 + ca + 1] : f6[p * 13 + ca - 8];
        }
      }
      __builtin_amdgcn_sched_barrier(0);  // pin load issue above the writer
    }

    writer_phase(LDS, COFF, l, y0, cw0, Wr, out, out6);

    // ---- commit tile-1 F to LDS (vmcnt wait lands here, post-writer) ----
    if (t1ok) {
      {
        int e = l;
        if (e < 110) {
          int px = e / 11, pr = e - px * 11;
          unsigned int pk = (unsigned int)bf16u(s_v0_0) | ((unsigned int)bf16u(s_v1_0) << 16);
          *(unsigned int*)&LDS[SOFF + px * 24 + 2 * pr] = pk;
        } else if (e < 120) {
          *(unsigned int*)&LDS[SOFF + (e - 110) * 24 + 22] = 0u;
        }
      }
      {
        int e = 64 + l;
        if (e < 110) {
          int px = e / 11, pr = e - px * 11;
          unsigned int pk = (unsigned int)bf16u(s_v0_1) | ((unsigned int)bf16u(s_v1_1) << 16);
          *(unsigned int*)&LDS[SOFF + px * 24 + 2 * pr] = pk;
        }
      }
    }
    WAVE_LDS_FENCE();  // covers writer ds_reads + tile-1 F ds_writes
  }

  // ================= tile 1 =================
  if (t1ok) {
    compute_phase(LDS, SOFF, COFF, l, l15, lg, q, lcell, a0);
    writer_phase(LDS, COFF, l, y1, cw1, Wr, out, out6);
  }
}

extern "C" void kernel_launch(void* const* d_in, const int* in_sizes, int n_in,
                              void* d_out, int out_size, void* d_ws, size_t ws_size,
                              hipStream_t stream) {
  const float* f4 = (const float*)d_in[0];
  const float* f6 = (const float*)d_in[1];
  const int* ph = (const int*)d_in[2];
  const int* pw = (const int*)d_in[3];
  const float* wagg = (const float*)d_in[4];
  const float* wtp = (const float*)d_in[5];
  float* out = (float*)d_out;
  unsigned short* wsu = (unsigned short*)d_ws;

  long long HW = (long long)in_sizes[0] / 9;
  long long tail = (long long)out_size - 2;

  eq_setup<<<104, 256, 0, stream>>>(wagg, wtp, ph, pw, out, tail, wsu);

  int S = (int)(sqrt((double)HW) + 0.5);
  long long nb;
  if ((long long)S * S == HW) {
    long long nt = (long long)((S + 31) / 32) * S;  // square image (the bench case)
    nb = (nt + 1) / 2;
  } else {
    nb = HW / 2 + 2;  // conservative cover; excess blocks exit after the barrier
  }
  eq_main<<<(int)nb, 512, 0, stream>>>(f4, f6, ph, pw, wsu, out);
}